// Round 7
// baseline (331.548 us; speedup 1.0000x reference)
//
#include <hip/hip_runtime.h>
#include <hip/hip_bf16.h>

// PointNetConv on MI355X (gfx950) — round 14. f32 inputs.
// Algebra: h1 = relu(A[row] - P[col]),  A = x@W1x + b1 + pos@W1p,  P = pos@W1p.
//
// r13: 267us total; pernode 131us, VGPR 128, 0 conflicts. Pipe model/CU:
// LDS 190K cyc (60%, top pipe: 32 ds_read_b128 x 12cyc per 16-edge chunk),
// VALU 119K (45% = counter), MFMA 79K (25% ~= counter). LDS-bound.
//
// r14: pair-chunk B-share. Same CSR node-stream + 3-level prefetch (r11's
// stream-model rewrite is NOT repeated), but pipeline advances 2 chunks/iter:
// compute (d0,d1), A-prefetch (d2,d3), srow-prefetch (d4,d5). B-sweep reads
// each W2 fragment ONCE and feeds 2 MFMAs -> LDS per edge halves. Register
// discipline: nt-pair sweep (16 f32 acc live), accA folds inline, accB via
// mB[8]; P register-resident, boundary P loads at rotate (1 iter of cover).

typedef _Float16 f16_t;
typedef _Float16 f16x8 __attribute__((ext_vector_type(8)));
typedef float    f32x4 __attribute__((ext_vector_type(4)));

#define DPAD 16
#define NSB_SHIFT 8          // 256 nodes per superbucket
#define SBCAP 9216           // per-bucket edge cap (mean 8192, +11 sigma)
#define PA_TILE 2048         // edges per passA tile

__device__ __forceinline__ f16x8 sub_relu8(f16x8 a, f16x8 b) {
  f16x8 d = a - b;                          // v_pk_add_f16 (neg)
  f16x8 z = {};
  return __builtin_elementwise_max(d, z);   // v_pk_max_f16
}

// ---------------- fallback scan chain (proven r7) ----------------
__global__ __launch_bounds__(256) void tilesum_kernel(const int* __restrict__ dpad,
                                                      int* __restrict__ tsum, int N) {
  __shared__ int ws[4];
  int tid = threadIdx.x;
  int i = blockIdx.x * 256 + tid;
  int v = (i < N) ? dpad[(long)i * DPAD] : 0;
#pragma unroll
  for (int off = 32; off > 0; off >>= 1) v += __shfl_down(v, off, 64);
  if ((tid & 63) == 0) ws[tid >> 6] = v;
  __syncthreads();
  if (tid == 0) tsum[blockIdx.x] = ws[0] + ws[1] + ws[2] + ws[3];
}

__global__ __launch_bounds__(256) void tscan_kernel(const int* __restrict__ tsum,
                                                    int* __restrict__ texcl,
                                                    int* __restrict__ startN, int nt_) {
  __shared__ int wsum[4];
  int tid = threadIdx.x, lane = tid & 63, w = tid >> 6;
  int v = (tid < nt_) ? tsum[tid] : 0;
  int s = v;
#pragma unroll
  for (int off = 1; off < 64; off <<= 1) {
    int t = __shfl_up(s, off, 64);
    if (lane >= off) s += t;
  }
  if (lane == 63) wsum[w] = s;
  __syncthreads();
  int add = 0;
  for (int j = 0; j < w; ++j) add += wsum[j];
  if (tid < nt_) texcl[tid] = add + s - v;
  if (tid == 0) *startN = wsum[0] + wsum[1] + wsum[2] + wsum[3];
}

__global__ __launch_bounds__(256) void scanout_kernel(int* __restrict__ dpad,
                                                      const int* __restrict__ texcl,
                                                      int* __restrict__ start, int N) {
  __shared__ int wsum[4];
  int tid = threadIdx.x, lane = tid & 63, w = tid >> 6;
  int i = blockIdx.x * 256 + tid;
  int v = (i < N) ? dpad[(long)i * DPAD] : 0;
  int s = v;
#pragma unroll
  for (int off = 1; off < 64; off <<= 1) {
    int t = __shfl_up(s, off, 64);
    if (lane >= off) s += t;
  }
  if (lane == 63) wsum[w] = s;
  __syncthreads();
  int add = texcl[blockIdx.x];
  for (int j = 0; j < w; ++j) add += wsum[j];
  int excl = add + s - v;
  if (i < N) { start[i] = excl; dpad[(long)i * DPAD + 8] = excl; }
}

__global__ __launch_bounds__(256) void scatter_kernel(const int* __restrict__ eidx,
                                                      int* __restrict__ dpad,
                                                      int* __restrict__ srow, int E) {
  int i = blockIdx.x * 256 + threadIdx.x;
  if (i < E) {
    int slot = atomicAdd(&dpad[(long)eidx[E + i] * DPAD + 8], 1);
    srow[slot] = eidx[i];
  }
}

__device__ __forceinline__ f16x8 load_frag8h(const float* p) {
  float4 a = *(const float4*)p;
  float4 b = *(const float4*)(p + 4);
  f16x8 r;
  r[0] = (f16_t)a.x; r[1] = (f16_t)a.y; r[2] = (f16_t)a.z; r[3] = (f16_t)a.w;
  r[4] = (f16_t)b.x; r[5] = (f16_t)b.y; r[6] = (f16_t)b.z; r[7] = (f16_t)b.w;
  return r;
}

// ---------------------------------------------------------------------------
// Shared-memory structs for the role-split kernels (union via char buffer).
// ---------------------------------------------------------------------------
struct GemmSmem {
  f16_t ws_[8][4][64][8];    // 32768 B
  float w1ps[3][128];        //  1536 B
  float bs_[128];            //   512 B
  float pos_s[64][3];        //   768 B
};                           // 35584 B

struct PassASmem {
  unsigned sorted[PA_TILE];       // 8192 B
  unsigned char sbb[PA_TILE];     // 2048 B
  int hist[256];
  int off_[256];
  int cur[256];
  int gbase[256];
  int scanb[256];
};                                // 15360 B

#define SMEM_BYTES 35840

// ---------------------------------------------------------------------------
// AP-GEMM body: A = x@W1x + b1 + pos@W1p, P = pos@W1p (f16 into d_out).
// ---------------------------------------------------------------------------
__device__ __forceinline__ void ap_gemm_body(
    const float* __restrict__ x, const float* __restrict__ pos,
    const float* __restrict__ W1, const float* __restrict__ b1,
    f16_t* __restrict__ Abuf, f16_t* __restrict__ Pbuf, int N, int blk,
    char* smem)
{
  GemmSmem* G = (GemmSmem*)smem;
  const int tid = threadIdx.x;
  for (int it = tid; it < 8 * 4 * 64; it += 256) {
    int nt = it >> 8, kt = (it >> 6) & 3, l = it & 63;
    int n = nt * 16 + (l & 15), quad = l >> 4;
    f16x8 v;
#pragma unroll
    for (int j = 0; j < 8; ++j) v[j] = (f16_t)W1[(kt * 32 + quad * 8 + j) * 128 + n];
    *(f16x8*)&G->ws_[nt][kt][l][0] = v;
  }
  for (int it = tid; it < 384; it += 256)
    G->w1ps[it >> 7][it & 127] = W1[(128 + (it >> 7)) * 128 + (it & 127)];
  if (tid < 128) G->bs_[tid] = b1[tid];
  {
    int g = blk * 192 + tid;
    if (tid < 192 && g < 3 * N) G->pos_s[tid / 3][tid % 3] = pos[g];
  }
  __syncthreads();

  const int w = tid >> 6, lane = tid & 63;
  const int m15 = lane & 15, quad = lane >> 4;

  int node_a = blk * 64 + w * 16 + m15;
  const float* xrow = x + (long)min(node_a, N - 1) * 128;
  f16x8 a[4];
#pragma unroll
  for (int kt = 0; kt < 4; ++kt)
    a[kt] = load_frag8h(xrow + kt * 32 + quad * 8);

  f32x4 acc[8];
#pragma unroll
  for (int nt = 0; nt < 8; ++nt) acc[nt] = (f32x4){0.f, 0.f, 0.f, 0.f};
#pragma unroll
  for (int nt = 0; nt < 8; ++nt)
#pragma unroll
    for (int kt = 0; kt < 4; ++kt)
      acc[nt] = __builtin_amdgcn_mfma_f32_16x16x32_f16(
          a[kt], *(const f16x8*)&G->ws_[nt][kt][lane][0], acc[nt], 0, 0, 0);

#pragma unroll
  for (int r = 0; r < 4; ++r) {
    int nl = w * 16 + quad * 4 + r;
    int node = blk * 64 + nl;
    if (node < N) {
      float p0 = G->pos_s[nl][0], p1 = G->pos_s[nl][1], p2 = G->pos_s[nl][2];
#pragma unroll
      for (int nt = 0; nt < 8; ++nt) {
        int c = nt * 16 + m15;
        float pv = p0 * G->w1ps[0][c] + p1 * G->w1ps[1][c] + p2 * G->w1ps[2][c];
        long idx = (long)node * 128 + c;
        Abuf[idx] = (f16_t)(acc[nt][r] + G->bs_[c] + pv);
        Pbuf[idx] = (f16_t)pv;
      }
    }
  }
}

// ---------------------------------------------------------------------------
// passA body: tile-sort PA_TILE edges into superbuckets, all random ops in
// LDS; ~NSB aggregated global atomics per tile; coalesced u32 segment writes.
// Entry format: (col&255)<<24 | row.
// ---------------------------------------------------------------------------
__device__ __forceinline__ void passa_body(
    const int* __restrict__ eidx, unsigned* __restrict__ pairsBuf,
    int* __restrict__ superCursor, int E, int tile, char* smem)
{
  PassASmem* S = (PassASmem*)smem;
  const int tid = threadIdx.x;
  const int base = tile * PA_TILE;
  const int cnt_t = min(PA_TILE, E - base);

  for (int j = tid; j < 256; j += 256) S->hist[j] = 0;
  __syncthreads();

  int myrow[8], mycol[8];
#pragma unroll
  for (int k = 0; k < 8; ++k) {
    int idx = k * 256 + tid;
    int i = base + idx;
    if (idx < cnt_t) {
      myrow[k] = eidx[i];
      mycol[k] = eidx[E + i];
      atomicAdd(&S->hist[mycol[k] >> NSB_SHIFT], 1);
    } else mycol[k] = -1;
  }
  __syncthreads();

  int v = S->hist[tid];
  S->scanb[tid] = v;
  __syncthreads();
  for (int d = 1; d < 256; d <<= 1) {
    int t = (tid >= d) ? S->scanb[tid - d] : 0;
    __syncthreads();
    S->scanb[tid] += t;
    __syncthreads();
  }
  int excl = S->scanb[tid] - v;
  S->off_[tid] = excl;
  S->cur[tid]  = excl;
  S->gbase[tid] = (v > 0) ? atomicAdd(&superCursor[tid * 16], v) : 0;
  __syncthreads();

#pragma unroll
  for (int k = 0; k < 8; ++k) {
    if (mycol[k] >= 0) {
      int sb = mycol[k] >> NSB_SHIFT;
      int pos = atomicAdd(&S->cur[sb], 1);
      S->sorted[pos] = ((unsigned)(mycol[k] & 255) << 24) | (unsigned)myrow[k];
      S->sbb[pos] = (unsigned char)sb;
    }
  }
  __syncthreads();

#pragma unroll
  for (int k = 0; k < 8; ++k) {
    int idx = k * 256 + tid;
    if (idx < cnt_t) {
      int sb = S->sbb[idx];
      int local = idx - S->off_[sb];
      int g = S->gbase[sb] + local;
      if (g < SBCAP) pairsBuf[(long)sb * SBCAP + g] = S->sorted[idx];
    }
  }
}

// fusedA: AP-GEMM role + passA role in one launch (overlap).
__global__ __launch_bounds__(256) void fusedA_kernel(
    const float* __restrict__ x, const float* __restrict__ pos,
    const int* __restrict__ eidx, const float* __restrict__ W1,
    const float* __restrict__ b1, unsigned* __restrict__ pairsBuf,
    int* __restrict__ superCursor, f16_t* __restrict__ Abuf,
    f16_t* __restrict__ Pbuf, int N, int E, int nodeBlocks)
{
  __shared__ __align__(16) char smem[SMEM_BYTES];
  if ((int)blockIdx.x >= nodeBlocks) {
    passa_body(eidx, pairsBuf, superCursor, E, (int)blockIdx.x - nodeBlocks, smem);
    return;
  }
  ap_gemm_body(x, pos, W1, b1, Abuf, Pbuf, N, blockIdx.x, smem);
}

// Fallback path: hist role + AP-GEMM role (r7-proven).
__global__ __launch_bounds__(256) void fused_hist_kernel(
    const float* __restrict__ x, const float* __restrict__ pos,
    const int* __restrict__ eidx, const float* __restrict__ W1,
    const float* __restrict__ b1, int* __restrict__ dpad,
    f16_t* __restrict__ Abuf, f16_t* __restrict__ Pbuf,
    int N, int E, int nodeBlocks)
{
  __shared__ __align__(16) char smem[SMEM_BYTES];
  if ((int)blockIdx.x >= nodeBlocks) {
    int i = ((int)blockIdx.x - nodeBlocks) * 256 + threadIdx.x;
    if (i < E) atomicAdd(&dpad[(long)eidx[E + i] * DPAD], 1);
    return;
  }
  ap_gemm_body(x, pos, W1, b1, Abuf, Pbuf, N, blockIdx.x, smem);
}

// ---------------------------------------------------------------------------
// passB: one block per superbucket; exact per-node CSR built in LDS from u32
// pairs. Emits r10-format CSR: srow (row indices), startB[n], endB[n].
// ---------------------------------------------------------------------------
__global__ __launch_bounds__(256) void passb_kernel(
    const unsigned* __restrict__ pairsA, const int* __restrict__ superCursor,
    int* __restrict__ srow, int* __restrict__ startB, int* __restrict__ endB,
    int N)
{
  __shared__ int rows[SBCAP];     // 36 KB
  __shared__ int deg[256], scanb[256], cur[256];
  const int sb = blockIdx.x, tid = threadIdx.x;
  const int cntIn = min(superCursor[sb * 16], SBCAP);
  const unsigned* Pin = pairsA + (long)sb * SBCAP;

  deg[tid] = 0;
  __syncthreads();
  for (int i = tid; i < cntIn; i += 256)
    atomicAdd(&deg[Pin[i] >> 24], 1);
  __syncthreads();
  int d = deg[tid];
  scanb[tid] = d;
  __syncthreads();
  for (int s = 1; s < 256; s <<= 1) {
    int t2 = (tid >= s) ? scanb[tid - s] : 0;
    __syncthreads();
    scanb[tid] += t2;
    __syncthreads();
  }
  int excl = scanb[tid] - d;
  cur[tid] = excl;
  int n = (sb << NSB_SHIFT) + tid;
  if (n < N) {
    startB[n] = sb * SBCAP + excl;
    endB[n]   = sb * SBCAP + excl + d;
  }
  __syncthreads();
  for (int i = tid; i < cntIn; i += 256) {
    unsigned p = Pin[i];
    int slot = atomicAdd(&cur[p >> 24], 1);
    rows[slot] = (int)(p & 0xFFFFFFu);
  }
  __syncthreads();
  const int gb = sb * SBCAP;
  for (int i = tid; i < cntIn; i += 256) srow[gb + i] = rows[i];
}

// ---------------------------------------------------------------------------
// pernode r14: pair-chunk stream. Per wave, advance TWO 16-edge chunks per
// iteration: compute (d0,d1), A-prefetch (d2,d3), srow-prefetch (d4,d5).
// B-sweep reads each W2 fragment once, feeds both chunks' MFMAs (LDS/edge
// halved). nt-pair sweep keeps 16 f32 acc live; accA folds into runmax
// inline, accB via mB[8] merged after the mid-pair boundary check.
// ---------------------------------------------------------------------------
__global__ __launch_bounds__(256) void pernode_kernel(
    const f16_t* __restrict__ Abuf, const f16_t* __restrict__ Pbuf,
    const float* __restrict__ W2, const float* __restrict__ b2,
    const int* __restrict__ startp, const int* __restrict__ endp,
    const int* __restrict__ srow, f16_t* __restrict__ maxbf, int N)
{
  __shared__ f16_t w2s[8][4][64][8];   // 32 KB, B-fragment-major
  __shared__ float b2s[128];

  const int tid = threadIdx.x;
  for (int it = tid; it < 8 * 4 * 64; it += 256) {
    int nt = it >> 8, kt = (it >> 6) & 3, l = it & 63;
    int ncol = nt * 16 + (l & 15), q = l >> 4;
    f16x8 v;
#pragma unroll
    for (int j = 0; j < 8; ++j) v[j] = (f16_t)W2[(kt * 32 + q * 8 + j) * 128 + ncol];
    *(f16x8*)&w2s[nt][kt][l][0] = v;
  }
  if (tid < 128) b2s[tid] = b2[tid];
  __syncthreads();

  const int w = tid >> 6, lane = tid & 63;
  const int m15 = lane & 15, quad = lane >> 4;

  const int nslots = (int)gridDim.x * 4;
  const int slot   = (int)blockIdx.x * 4 + w;
  const int K      = (N + nslots - 1) / nslots;
  const int nBeg   = slot * K;
  const int nEnd   = min(N, nBeg + K);
  if (nBeg >= nEnd) return;

  auto adv = [&](int& n, int& c, int& e) {
    c += 16;
    if (c < e) return;
    for (;;) {
      if (++n >= nEnd) { n = nEnd; c -= 16; return; }
      int s_ = startp[n], e_ = endp[n];
      if (e_ > s_) { c = s_; e = e_; return; }
      if (quad == 0) {
#pragma unroll
        for (int nt = 0; nt < 8; ++nt)
          maxbf[(long)n * 128 + nt * 16 + m15] = (f16_t)0.f;
      }
    }
  };

  // six chunk descriptors
  int n0 = nBeg - 1, c0 = -16, e0 = 0; adv(n0, c0, e0);
  if (n0 >= nEnd) return;
  int n1 = n0, c1 = c0, e1 = e0; adv(n1, c1, e1);
  int n2 = n1, c2 = c1, e2 = e1; adv(n2, c2, e2);
  int n3 = n2, c3 = c2, e3 = e2; adv(n3, c3, e3);
  int n4 = n3, c4 = c3, e4 = e3; adv(n4, c4, e4);
  int n5 = n4, c5 = c4, e5 = e4; adv(n5, c5, e5);

  // rows: compute pair (direct), prefetch pair, tail pair
  int rA0 = srow[min(c0 + m15, e0 - 1)];
  int rB0 = srow[min(c1 + m15, e1 - 1)];
  int rA1 = srow[min(c2 + m15, e2 - 1)];
  int rB1 = srow[min(c3 + m15, e3 - 1)];
  int rA2 = srow[min(c4 + m15, e4 - 1)];
  int rB2 = srow[min(c5 + m15, e5 - 1)];

  f16x8 xvA[4], xvB[4];
#pragma unroll
  for (int kt = 0; kt < 4; ++kt) {
    xvA[kt] = *(const f16x8*)(Abuf + (long)rA0 * 128 + kt * 32 + quad * 8);
    xvB[kt] = *(const f16x8*)(Abuf + (long)rB0 * 128 + kt * 32 + quad * 8);
  }

  f16x8 PnC[4], PnN[4];
#pragma unroll
  for (int kt = 0; kt < 4; ++kt)
    PnC[kt] = *(const f16x8*)(Pbuf + (long)n0 * 128 + kt * 32 + quad * 8);
  if (n1 != n0 && n1 < nEnd) {
#pragma unroll
    for (int kt = 0; kt < 4; ++kt)
      PnN[kt] = *(const f16x8*)(Pbuf + (long)n1 * 128 + kt * 32 + quad * 8);
  } else {
#pragma unroll
    for (int kt = 0; kt < 4; ++kt) PnN[kt] = PnC[kt];
  }

  float runmax[8];
#pragma unroll
  for (int nt = 0; nt < 8; ++nt) runmax[nt] = -3.4e38f;

  auto finishNode = [&](int g) {
#pragma unroll
    for (int nt = 0; nt < 8; ++nt) {
      float v = runmax[nt];
      v = fmaxf(v, __shfl_xor(v, 16, 64));
      v = fmaxf(v, __shfl_xor(v, 32, 64));
      v += b2s[nt * 16 + m15];
      if (quad == 0) maxbf[(long)g * 128 + nt * 16 + m15] = (f16_t)v;
    }
  };

  for (;;) {
    // A-prefetch for (d2,d3)
    f16x8 xnA[4], xnB[4];
#pragma unroll
    for (int kt = 0; kt < 4; ++kt) {
      xnA[kt] = *(const f16x8*)(Abuf + (long)rA1 * 128 + kt * 32 + quad * 8);
      xnB[kt] = *(const f16x8*)(Abuf + (long)rB1 * 128 + kt * 32 + quad * 8);
    }

    // h1 = relu(A - P), packed f16, in place
#pragma unroll
    for (int kt = 0; kt < 4; ++kt) xvA[kt] = sub_relu8(xvA[kt], PnC[kt]);
#pragma unroll
    for (int kt = 0; kt < 4; ++kt) xvB[kt] = sub_relu8(xvB[kt], PnN[kt]);

    // shared-B sweep over nt-pairs: 4 acc chains, 8 LDS reads per np
    float mB[8];
#pragma unroll
    for (int np = 0; np < 4; ++np) {
      f32x4 A0 = (f32x4){0.f, 0.f, 0.f, 0.f}, A1 = A0, B0 = A0, B1 = A0;
#pragma unroll
      for (int kt = 0; kt < 4; ++kt) {
        f16x8 f0 = *(const f16x8*)&w2s[np * 2 + 0][kt][lane][0];
        f16x8 f1 = *(const f16x8*)&w2s[np * 2 + 1][kt][lane][0];
        A0 = __builtin_amdgcn_mfma_f32_16x16x32_f16(xvA[kt], f0, A0, 0, 0, 0);
        B0 = __builtin_amdgcn_mfma_f32_16x16x32_f16(xvB[kt], f0, B0, 0, 0, 0);
        A1 = __builtin_amdgcn_mfma_f32_16x16x32_f16(xvA[kt], f1, A1, 0, 0, 0);
        B1 = __builtin_amdgcn_mfma_f32_16x16x32_f16(xvB[kt], f1, B1, 0, 0, 0);
      }
      runmax[np * 2 + 0] = fmaxf(runmax[np * 2 + 0],
          fmaxf(fmaxf(A0[0], A0[1]), fmaxf(A0[2], A0[3])));
      runmax[np * 2 + 1] = fmaxf(runmax[np * 2 + 1],
          fmaxf(fmaxf(A1[0], A1[1]), fmaxf(A1[2], A1[3])));
      mB[np * 2 + 0] = fmaxf(fmaxf(B0[0], B0[1]), fmaxf(B0[2], B0[3]));
      mB[np * 2 + 1] = fmaxf(fmaxf(B1[0], B1[1]), fmaxf(B1[2], B1[3]));
    }

    // mid-pair boundary: d1 entered a new node -> finish d0's node
    if (n1 != n0) {
      finishNode(n0);
#pragma unroll
      for (int nt = 0; nt < 8; ++nt) runmax[nt] = mB[nt];
    } else {
#pragma unroll
      for (int nt = 0; nt < 8; ++nt) runmax[nt] = fmaxf(runmax[nt], mB[nt]);
    }

    // end-pair boundary: d2 enters a new node -> finish d1's node
    // (if d1 frozen, n2 == n1 and this never triggers)
    if (n2 != n1) {
      finishNode(n1);
#pragma unroll
      for (int nt = 0; nt < 8; ++nt) runmax[nt] = -3.4e38f;
    }

    // rotate compute pair <- prefetch pair
    const int on1 = n1;
    n0 = n2; c0 = c2; e0 = e2;
    n1 = n3; c1 = c3; e1 = e3;
    if (n0 >= nEnd) break;
#pragma unroll
    for (int kt = 0; kt < 4; ++kt) { xvA[kt] = xnA[kt]; xvB[kt] = xnB[kt]; }

    // P update for new front nodes (monotone: n0 != on1 => strictly new)
    if (n0 == on1) {
#pragma unroll
      for (int kt = 0; kt < 4; ++kt) PnC[kt] = PnN[kt];
    } else {
#pragma unroll
      for (int kt = 0; kt < 4; ++kt)
        PnC[kt] = *(const f16x8*)(Pbuf + (long)n0 * 128 + kt * 32 + quad * 8);
    }
    if (n1 != n0 && n1 < nEnd) {
#pragma unroll
      for (int kt = 0; kt < 4; ++kt)
        PnN[kt] = *(const f16x8*)(Pbuf + (long)n1 * 128 + kt * 32 + quad * 8);
    } else {
#pragma unroll
      for (int kt = 0; kt < 4; ++kt) PnN[kt] = PnC[kt];
    }

    // rotate prefetch pair <- tail pair; advance tail; issue its srow
    n2 = n4; c2 = c4; e2 = e4;
    n3 = n5; c3 = c5; e3 = e5;
    rA1 = rA2; rB1 = rB2;
    n4 = n5; c4 = c5; e4 = e5; adv(n4, c4, e4);
    rA2 = srow[min(c4 + m15, e4 - 1)];
    n5 = n4; c5 = c4; e5 = e4; adv(n5, c5, e5);
    rB2 = srow[min(c5 + m15, e5 - 1)];
  }
}

// ---------------------------------------------------------------------------
// final: d_out = maxbf + x @ Wr + br   (f32 out)
// ---------------------------------------------------------------------------
__global__ __launch_bounds__(256) void final_gemm_kernel(
    const float* __restrict__ xin, const float* __restrict__ W,
    const float* __restrict__ bias, const f16_t* __restrict__ maxv,
    float* __restrict__ dst, int N)
{
  __shared__ f16_t ws_[8][4][64][8];
  __shared__ float bs_[128];

  const int tid = threadIdx.x;
  for (int it = tid; it < 8 * 4 * 64; it += 256) {
    int nt = it >> 8, kt = (it >> 6) & 3, l = it & 63;
    int n = nt * 16 + (l & 15), quad = l >> 4;
    f16x8 v;
#pragma unroll
    for (int j = 0; j < 8; ++j) v[j] = (f16_t)W[(kt * 32 + quad * 8 + j) * 128 + n];
    *(f16x8*)&ws_[nt][kt][l][0] = v;
  }
  if (tid < 128) bs_[tid] = bias[tid];
  __syncthreads();

  const int w = tid >> 6, lane = tid & 63;
  const int m15 = lane & 15, quad = lane >> 4;

  int node_a = blockIdx.x * 64 + w * 16 + m15;
  const float* xrow = xin + (long)min(node_a, N - 1) * 128;
  f16x8 a[4];
#pragma unroll
  for (int kt = 0; kt < 4; ++kt)
    a[kt] = load_frag8h(xrow + kt * 32 + quad * 8);

  f32x4 acc[8];
#pragma unroll
  for (int nt = 0; nt < 8; ++nt) acc[nt] = (f32x4){0.f, 0.f, 0.f, 0.f};
#pragma unroll
  for (int nt = 0; nt < 8; ++nt)
#pragma unroll
    for (int kt = 0; kt < 4; ++kt)
      acc[nt] = __builtin_amdgcn_mfma_f32_16x16x32_f16(
          a[kt], *(const f16x8*)&ws_[nt][kt][lane][0], acc[nt], 0, 0, 0);

#pragma unroll
  for (int r = 0; r < 4; ++r) {
    int node = blockIdx.x * 64 + w * 16 + quad * 4 + r;
    if (node < N) {
#pragma unroll
      for (int nt = 0; nt < 8; ++nt) {
        int c = nt * 16 + m15;
        long idx = (long)node * 128 + c;
        dst[idx] = acc[nt][r] + bs_[c] + (float)maxv[idx];
      }
    }
  }
}

extern "C" void kernel_launch(void* const* d_in, const int* in_sizes, int n_in,
                              void* d_out, int out_size, void* d_ws, size_t ws_size,
                              hipStream_t stream) {
  (void)n_in; (void)out_size;
  const float* x   = (const float*)d_in[0];
  const float* pos = (const float*)d_in[1];
  const int*   eix = (const int*)d_in[2];
  const float* W1  = (const float*)d_in[3];
  const float* b1  = (const float*)d_in[4];
  const float* W2  = (const float*)d_in[5];
  const float* b2  = (const float*)d_in[6];
  const float* Wr  = (const float*)d_in[7];
  const float* br  = (const float*)d_in[8];

  const int N = in_sizes[0] / 128;
  const int E = in_sizes[2] / 2;

  f16_t* Abuf = (f16_t*)d_out;                      // [0, N*128) f16
  f16_t* Pbuf = (f16_t*)d_out + (size_t)N * 128;    // [N*128, N*256) f16

  const int nodeBlocks = (N + 63) / 64;
  const int edgeBlocks = (E + 255) / 256;
  const int nTiles     = (N + 255) / 256;
  const int NSB        = (N + 255) >> NSB_SHIFT;
  const int paBlocks   = (E + PA_TILE - 1) / PA_TILE;

  f16_t* maxbf = (f16_t*)d_ws;                      // N*256 B

  // packed path ws: maxbf + pairsA + srow + start/end + superCursor
  const size_t needPack = (size_t)N * 256 + (size_t)NSB * SBCAP * 8 +
                          (size_t)N * 8 + (size_t)NSB * 64 + 1024;

  if (ws_size >= needPack && NSB <= 256 && N < (1 << 24)) {
    // ---------------- u32-bucketed CSR path ----------------
    unsigned* pairsA      = (unsigned*)((char*)d_ws + (size_t)N * 256);
    int*      srowN       = (int*)(pairsA + (size_t)NSB * SBCAP);
    int*      startB      = (int*)(srowN + (size_t)NSB * SBCAP);
    int*      endB        = startB + N;
    int*      superCursor = endB + N;

    hipMemsetAsync(superCursor, 0, (size_t)NSB * 64, stream);
    fusedA_kernel<<<nodeBlocks + paBlocks, 256, 0, stream>>>(
        x, pos, eix, W1, b1, pairsA, superCursor, Abuf, Pbuf, N, E, nodeBlocks);
    passb_kernel<<<NSB, 256, 0, stream>>>(pairsA, superCursor, srowN,
                                          startB, endB, N);
    pernode_kernel<<<2048, 256, 0, stream>>>(Abuf, Pbuf, W2, b2, startB, endB,
                                             srowN, maxbf, N);
  } else {
    // ---------------- fallback: r7 hist+scan+scatter ----------------
    int* srow  = (int*)((char*)d_ws + (size_t)N * 256);
    int* dpad  = srow + E;
    int* start = dpad + (size_t)N * DPAD;
    int* tsum  = start + N + 1;
    int* texcl = tsum + 256;

    hipMemsetAsync(dpad, 0, (size_t)N * DPAD * 4, stream);
    fused_hist_kernel<<<nodeBlocks + edgeBlocks, 256, 0, stream>>>(
        x, pos, eix, W1, b1, dpad, Abuf, Pbuf, N, E, nodeBlocks);
    tilesum_kernel<<<nTiles, 256, 0, stream>>>(dpad, tsum, N);
    tscan_kernel<<<1, 256, 0, stream>>>(tsum, texcl, &start[N], nTiles);
    scanout_kernel<<<nTiles, 256, 0, stream>>>(dpad, texcl, start, N);
    scatter_kernel<<<edgeBlocks, 256, 0, stream>>>(eix, dpad, srow, E);
    pernode_kernel<<<2048, 256, 0, stream>>>(Abuf, Pbuf, W2, b2, start, start + 1,
                                             srow, maxbf, N);
  }

  final_gemm_kernel<<<nodeBlocks, 256, 0, stream>>>(x, Wr, br, maxbf,
                                                    (float*)d_out, N);
}

// Round 8
// 285.322 us; speedup vs baseline: 1.1620x; 1.1620x over previous
//
#include <hip/hip_runtime.h>
#include <hip/hip_bf16.h>

// PointNetConv on MI355X (gfx950) — round 15. f32 inputs.
// Algebra: h1 = relu(A[row] - P[col]),  A = x@W1x + b1 + pos@W1p,  P = pos@W1p.
//
// r14 post-mortem: pair-chunk B-share halved LDS but VGPR 164 -> 3 waves/SIMD
// -> 195us (vs 131). -25% occupancy -> +49% time: the r13 point is
// CONCURRENCY-limited, not LDS-throughput-limited. All W2-register schemes
// cost >=140 VGPR -> wrong side of the 128 cliff. Operating point: <=128 VGPR.
//
// r15: (1) pernode unroll-by-2 ping-pong (X0/X1 role swap kills the 16
// v_mov/chunk rotate, same live set as r13); (2) fold x@Wr+br into fusedA
// via ws_ restage (A-frags already in regs), final becomes elementwise add
// (gated on ws >= ~53MB, silent fallback to old final_gemm).

typedef _Float16 f16_t;
typedef _Float16 f16x8 __attribute__((ext_vector_type(8)));
typedef _Float16 f16x4 __attribute__((ext_vector_type(4)));
typedef float    f32x4 __attribute__((ext_vector_type(4)));

#define DPAD 16
#define NSB_SHIFT 8          // 256 nodes per superbucket
#define SBCAP 9216           // per-bucket edge cap (mean 8192, +11 sigma)
#define PA_TILE 2048         // edges per passA tile

__device__ __forceinline__ f16x8 sub_relu8(f16x8 a, f16x8 b) {
  f16x8 d = a - b;                          // v_pk_add_f16 (neg)
  f16x8 z = {};
  return __builtin_elementwise_max(d, z);   // v_pk_max_f16
}

// ---------------- fallback scan chain (proven r7) ----------------
__global__ __launch_bounds__(256) void tilesum_kernel(const int* __restrict__ dpad,
                                                      int* __restrict__ tsum, int N) {
  __shared__ int ws[4];
  int tid = threadIdx.x;
  int i = blockIdx.x * 256 + tid;
  int v = (i < N) ? dpad[(long)i * DPAD] : 0;
#pragma unroll
  for (int off = 32; off > 0; off >>= 1) v += __shfl_down(v, off, 64);
  if ((tid & 63) == 0) ws[tid >> 6] = v;
  __syncthreads();
  if (tid == 0) tsum[blockIdx.x] = ws[0] + ws[1] + ws[2] + ws[3];
}

__global__ __launch_bounds__(256) void tscan_kernel(const int* __restrict__ tsum,
                                                    int* __restrict__ texcl,
                                                    int* __restrict__ startN, int nt_) {
  __shared__ int wsum[4];
  int tid = threadIdx.x, lane = tid & 63, w = tid >> 6;
  int v = (tid < nt_) ? tsum[tid] : 0;
  int s = v;
#pragma unroll
  for (int off = 1; off < 64; off <<= 1) {
    int t = __shfl_up(s, off, 64);
    if (lane >= off) s += t;
  }
  if (lane == 63) wsum[w] = s;
  __syncthreads();
  int add = 0;
  for (int j = 0; j < w; ++j) add += wsum[j];
  if (tid < nt_) texcl[tid] = add + s - v;
  if (tid == 0) *startN = wsum[0] + wsum[1] + wsum[2] + wsum[3];
}

__global__ __launch_bounds__(256) void scanout_kernel(int* __restrict__ dpad,
                                                      const int* __restrict__ texcl,
                                                      int* __restrict__ start, int N) {
  __shared__ int wsum[4];
  int tid = threadIdx.x, lane = tid & 63, w = tid >> 6;
  int i = blockIdx.x * 256 + tid;
  int v = (i < N) ? dpad[(long)i * DPAD] : 0;
  int s = v;
#pragma unroll
  for (int off = 1; off < 64; off <<= 1) {
    int t = __shfl_up(s, off, 64);
    if (lane >= off) s += t;
  }
  if (lane == 63) wsum[w] = s;
  __syncthreads();
  int add = texcl[blockIdx.x];
  for (int j = 0; j < w; ++j) add += wsum[j];
  int excl = add + s - v;
  if (i < N) { start[i] = excl; dpad[(long)i * DPAD + 8] = excl; }
}

__global__ __launch_bounds__(256) void scatter_kernel(const int* __restrict__ eidx,
                                                      int* __restrict__ dpad,
                                                      int* __restrict__ srow, int E) {
  int i = blockIdx.x * 256 + threadIdx.x;
  if (i < E) {
    int slot = atomicAdd(&dpad[(long)eidx[E + i] * DPAD + 8], 1);
    srow[slot] = eidx[i];
  }
}

__device__ __forceinline__ f16x8 load_frag8h(const float* p) {
  float4 a = *(const float4*)p;
  float4 b = *(const float4*)(p + 4);
  f16x8 r;
  r[0] = (f16_t)a.x; r[1] = (f16_t)a.y; r[2] = (f16_t)a.z; r[3] = (f16_t)a.w;
  r[4] = (f16_t)b.x; r[5] = (f16_t)b.y; r[6] = (f16_t)b.z; r[7] = (f16_t)b.w;
  return r;
}

// ---------------------------------------------------------------------------
// Shared-memory structs for the role-split kernels (union via char buffer).
// ---------------------------------------------------------------------------
struct GemmSmem {
  f16_t ws_[8][4][64][8];    // 32768 B
  float w1ps[3][128];        //  1536 B
  float bs_[128];            //   512 B
  float brs[128];            //   512 B
  float pos_s[64][3];        //   768 B
};                           // 36096 B

struct PassASmem {
  unsigned sorted[PA_TILE];       // 8192 B
  unsigned char sbb[PA_TILE];     // 2048 B
  int hist[256];
  int off_[256];
  int cur[256];
  int gbase[256];
  int scanb[256];
};                                // 15360 B

#define SMEM_BYTES 36096

// ---------------------------------------------------------------------------
// AP-GEMM body: A = x@W1x + b1 + pos@W1p, P = pos@W1p (f16 into d_out).
// If Rbuf != null: restage ws_ with Wr and also emit R = x@Wr + br (f32).
// ---------------------------------------------------------------------------
__device__ __forceinline__ void ap_gemm_body(
    const float* __restrict__ x, const float* __restrict__ pos,
    const float* __restrict__ W1, const float* __restrict__ b1,
    const float* __restrict__ Wr, const float* __restrict__ br_,
    f16_t* __restrict__ Abuf, f16_t* __restrict__ Pbuf,
    float* __restrict__ Rbuf, int N, int blk, char* smem)
{
  GemmSmem* G = (GemmSmem*)smem;
  const int tid = threadIdx.x;
  for (int it = tid; it < 8 * 4 * 64; it += 256) {
    int nt = it >> 8, kt = (it >> 6) & 3, l = it & 63;
    int n = nt * 16 + (l & 15), quad = l >> 4;
    f16x8 v;
#pragma unroll
    for (int j = 0; j < 8; ++j) v[j] = (f16_t)W1[(kt * 32 + quad * 8 + j) * 128 + n];
    *(f16x8*)&G->ws_[nt][kt][l][0] = v;
  }
  for (int it = tid; it < 384; it += 256)
    G->w1ps[it >> 7][it & 127] = W1[(128 + (it >> 7)) * 128 + (it & 127)];
  if (tid < 128) G->bs_[tid] = b1[tid];
  {
    int g = blk * 192 + tid;
    if (tid < 192 && g < 3 * N) G->pos_s[tid / 3][tid % 3] = pos[g];
  }
  __syncthreads();

  const int w = tid >> 6, lane = tid & 63;
  const int m15 = lane & 15, quad = lane >> 4;

  int node_a = blk * 64 + w * 16 + m15;
  const float* xrow = x + (long)min(node_a, N - 1) * 128;
  f16x8 a[4];
#pragma unroll
  for (int kt = 0; kt < 4; ++kt)
    a[kt] = load_frag8h(xrow + kt * 32 + quad * 8);

  f32x4 acc[8];
#pragma unroll
  for (int nt = 0; nt < 8; ++nt) acc[nt] = (f32x4){0.f, 0.f, 0.f, 0.f};
#pragma unroll
  for (int nt = 0; nt < 8; ++nt)
#pragma unroll
    for (int kt = 0; kt < 4; ++kt)
      acc[nt] = __builtin_amdgcn_mfma_f32_16x16x32_f16(
          a[kt], *(const f16x8*)&G->ws_[nt][kt][lane][0], acc[nt], 0, 0, 0);

#pragma unroll
  for (int r = 0; r < 4; ++r) {
    int nl = w * 16 + quad * 4 + r;
    int node = blk * 64 + nl;
    if (node < N) {
      float p0 = G->pos_s[nl][0], p1 = G->pos_s[nl][1], p2 = G->pos_s[nl][2];
#pragma unroll
      for (int nt = 0; nt < 8; ++nt) {
        int c = nt * 16 + m15;
        float pv = p0 * G->w1ps[0][c] + p1 * G->w1ps[1][c] + p2 * G->w1ps[2][c];
        long idx = (long)node * 128 + c;
        Abuf[idx] = (f16_t)(acc[nt][r] + G->bs_[c] + pv);
        Pbuf[idx] = (f16_t)pv;
      }
    }
  }

  if (Rbuf) {
    __syncthreads();                         // all waves done reading ws_ (W1)
    for (int it = tid; it < 8 * 4 * 64; it += 256) {
      int nt = it >> 8, kt = (it >> 6) & 3, l = it & 63;
      int n = nt * 16 + (l & 15), q = l >> 4;
      f16x8 v;
#pragma unroll
      for (int j = 0; j < 8; ++j) v[j] = (f16_t)Wr[(kt * 32 + q * 8 + j) * 128 + n];
      *(f16x8*)&G->ws_[nt][kt][l][0] = v;
    }
    if (tid < 128) G->brs[tid] = br_[tid];
    __syncthreads();

    f32x4 acc2[8];
#pragma unroll
    for (int nt = 0; nt < 8; ++nt) acc2[nt] = (f32x4){0.f, 0.f, 0.f, 0.f};
#pragma unroll
    for (int nt = 0; nt < 8; ++nt)
#pragma unroll
      for (int kt = 0; kt < 4; ++kt)
        acc2[nt] = __builtin_amdgcn_mfma_f32_16x16x32_f16(
            a[kt], *(const f16x8*)&G->ws_[nt][kt][lane][0], acc2[nt], 0, 0, 0);

#pragma unroll
    for (int r = 0; r < 4; ++r) {
      int node = blk * 64 + w * 16 + quad * 4 + r;
      if (node < N) {
#pragma unroll
        for (int nt = 0; nt < 8; ++nt) {
          int c = nt * 16 + m15;
          Rbuf[(long)node * 128 + c] = acc2[nt][r] + G->brs[c];
        }
      }
    }
  }
}

// ---------------------------------------------------------------------------
// passA body: tile-sort PA_TILE edges into superbuckets, all random ops in
// LDS; ~NSB aggregated global atomics per tile; coalesced u32 segment writes.
// Entry format: (col&255)<<24 | row.
// ---------------------------------------------------------------------------
__device__ __forceinline__ void passa_body(
    const int* __restrict__ eidx, unsigned* __restrict__ pairsBuf,
    int* __restrict__ superCursor, int E, int tile, char* smem)
{
  PassASmem* S = (PassASmem*)smem;
  const int tid = threadIdx.x;
  const int base = tile * PA_TILE;
  const int cnt_t = min(PA_TILE, E - base);

  for (int j = tid; j < 256; j += 256) S->hist[j] = 0;
  __syncthreads();

  int myrow[8], mycol[8];
#pragma unroll
  for (int k = 0; k < 8; ++k) {
    int idx = k * 256 + tid;
    int i = base + idx;
    if (idx < cnt_t) {
      myrow[k] = eidx[i];
      mycol[k] = eidx[E + i];
      atomicAdd(&S->hist[mycol[k] >> NSB_SHIFT], 1);
    } else mycol[k] = -1;
  }
  __syncthreads();

  int v = S->hist[tid];
  S->scanb[tid] = v;
  __syncthreads();
  for (int d = 1; d < 256; d <<= 1) {
    int t = (tid >= d) ? S->scanb[tid - d] : 0;
    __syncthreads();
    S->scanb[tid] += t;
    __syncthreads();
  }
  int excl = S->scanb[tid] - v;
  S->off_[tid] = excl;
  S->cur[tid]  = excl;
  S->gbase[tid] = (v > 0) ? atomicAdd(&superCursor[tid * 16], v) : 0;
  __syncthreads();

#pragma unroll
  for (int k = 0; k < 8; ++k) {
    if (mycol[k] >= 0) {
      int sb = mycol[k] >> NSB_SHIFT;
      int pos = atomicAdd(&S->cur[sb], 1);
      S->sorted[pos] = ((unsigned)(mycol[k] & 255) << 24) | (unsigned)myrow[k];
      S->sbb[pos] = (unsigned char)sb;
    }
  }
  __syncthreads();

#pragma unroll
  for (int k = 0; k < 8; ++k) {
    int idx = k * 256 + tid;
    if (idx < cnt_t) {
      int sb = S->sbb[idx];
      int local = idx - S->off_[sb];
      int g = S->gbase[sb] + local;
      if (g < SBCAP) pairsBuf[(long)sb * SBCAP + g] = S->sorted[idx];
    }
  }
}

// fusedA: AP-GEMM role + passA role in one launch (overlap).
__global__ __launch_bounds__(256) void fusedA_kernel(
    const float* __restrict__ x, const float* __restrict__ pos,
    const int* __restrict__ eidx, const float* __restrict__ W1,
    const float* __restrict__ b1, const float* __restrict__ Wr,
    const float* __restrict__ br_, unsigned* __restrict__ pairsBuf,
    int* __restrict__ superCursor, f16_t* __restrict__ Abuf,
    f16_t* __restrict__ Pbuf, float* __restrict__ Rbuf,
    int N, int E, int nodeBlocks)
{
  __shared__ __align__(16) char smem[SMEM_BYTES];
  if ((int)blockIdx.x >= nodeBlocks) {
    passa_body(eidx, pairsBuf, superCursor, E, (int)blockIdx.x - nodeBlocks, smem);
    return;
  }
  ap_gemm_body(x, pos, W1, b1, Wr, br_, Abuf, Pbuf, Rbuf, N, blockIdx.x, smem);
}

// Fallback path: hist role + AP-GEMM role (r7-proven).
__global__ __launch_bounds__(256) void fused_hist_kernel(
    const float* __restrict__ x, const float* __restrict__ pos,
    const int* __restrict__ eidx, const float* __restrict__ W1,
    const float* __restrict__ b1, int* __restrict__ dpad,
    f16_t* __restrict__ Abuf, f16_t* __restrict__ Pbuf,
    int N, int E, int nodeBlocks)
{
  __shared__ __align__(16) char smem[SMEM_BYTES];
  if ((int)blockIdx.x >= nodeBlocks) {
    int i = ((int)blockIdx.x - nodeBlocks) * 256 + threadIdx.x;
    if (i < E) atomicAdd(&dpad[(long)eidx[E + i] * DPAD], 1);
    return;
  }
  ap_gemm_body(x, pos, W1, b1, nullptr, nullptr, Abuf, Pbuf, nullptr, N,
               blockIdx.x, smem);
}

// ---------------------------------------------------------------------------
// passB: one block per superbucket; exact per-node CSR built in LDS from u32
// pairs. Emits r10-format CSR: srow (row indices), startB[n], endB[n].
// ---------------------------------------------------------------------------
__global__ __launch_bounds__(256) void passb_kernel(
    const unsigned* __restrict__ pairsA, const int* __restrict__ superCursor,
    int* __restrict__ srow, int* __restrict__ startB, int* __restrict__ endB,
    int N)
{
  __shared__ int rows[SBCAP];     // 36 KB
  __shared__ int deg[256], scanb[256], cur[256];
  const int sb = blockIdx.x, tid = threadIdx.x;
  const int cntIn = min(superCursor[sb * 16], SBCAP);
  const unsigned* Pin = pairsA + (long)sb * SBCAP;

  deg[tid] = 0;
  __syncthreads();
  for (int i = tid; i < cntIn; i += 256)
    atomicAdd(&deg[Pin[i] >> 24], 1);
  __syncthreads();
  int d = deg[tid];
  scanb[tid] = d;
  __syncthreads();
  for (int s = 1; s < 256; s <<= 1) {
    int t2 = (tid >= s) ? scanb[tid - s] : 0;
    __syncthreads();
    scanb[tid] += t2;
    __syncthreads();
  }
  int excl = scanb[tid] - d;
  cur[tid] = excl;
  int n = (sb << NSB_SHIFT) + tid;
  if (n < N) {
    startB[n] = sb * SBCAP + excl;
    endB[n]   = sb * SBCAP + excl + d;
  }
  __syncthreads();
  for (int i = tid; i < cntIn; i += 256) {
    unsigned p = Pin[i];
    int slot = atomicAdd(&cur[p >> 24], 1);
    rows[slot] = (int)(p & 0xFFFFFFu);
  }
  __syncthreads();
  const int gb = sb * SBCAP;
  for (int i = tid; i < cntIn; i += 256) srow[gb + i] = rows[i];
}

// ---------------------------------------------------------------------------
// pernode r15: r13's proven 3-level CSR stream, manually unrolled by 2 with
// X0/X1 ping-pong (no xv<-xn copies; identical live set -> VGPR ~128).
// ---------------------------------------------------------------------------
__global__ __launch_bounds__(256) void pernode_kernel(
    const f16_t* __restrict__ Abuf, const f16_t* __restrict__ Pbuf,
    const float* __restrict__ W2, const float* __restrict__ b2,
    const int* __restrict__ startp, const int* __restrict__ endp,
    const int* __restrict__ srow, f16_t* __restrict__ maxbf, int N)
{
  __shared__ f16_t w2s[8][4][64][8];   // 32 KB, B-fragment-major
  __shared__ float b2s[128];

  const int tid = threadIdx.x;
  for (int it = tid; it < 8 * 4 * 64; it += 256) {
    int nt = it >> 8, kt = (it >> 6) & 3, l = it & 63;
    int ncol = nt * 16 + (l & 15), q = l >> 4;
    f16x8 v;
#pragma unroll
    for (int j = 0; j < 8; ++j) v[j] = (f16_t)W2[(kt * 32 + q * 8 + j) * 128 + ncol];
    *(f16x8*)&w2s[nt][kt][l][0] = v;
  }
  if (tid < 128) b2s[tid] = b2[tid];
  __syncthreads();

  const int w = tid >> 6, lane = tid & 63;
  const int m15 = lane & 15, quad = lane >> 4;

  const int nslots = (int)gridDim.x * 4;
  const int slot   = (int)blockIdx.x * 4 + w;
  const int K      = (N + nslots - 1) / nslots;
  const int nBeg   = slot * K;
  const int nEnd   = min(N, nBeg + K);
  if (nBeg >= nEnd) return;

  auto adv = [&](int& n, int& c, int& e) {
    c += 16;
    if (c < e) return;
    for (;;) {
      if (++n >= nEnd) { n = nEnd; c -= 16; return; }
      int s_ = startp[n], e_ = endp[n];
      if (e_ > s_) { c = s_; e = e_; return; }
      if (quad == 0) {
#pragma unroll
        for (int nt = 0; nt < 8; ++nt)
          maxbf[(long)n * 128 + nt * 16 + m15] = (f16_t)0.f;
      }
    }
  };

  int n0 = nBeg - 1, c0 = -16, e0 = 0;
  adv(n0, c0, e0);
  if (n0 >= nEnd) return;

  f16x8 PnC[4], PnN[4];
#pragma unroll
  for (int kt = 0; kt < 4; ++kt)
    PnC[kt] = *(const f16x8*)(Pbuf + (long)n0 * 128 + kt * 32 + quad * 8);
  int r0 = srow[min(c0 + m15, e0 - 1)];

  int n1 = n0, c1 = c0, e1 = e0;
  adv(n1, c1, e1);

  f16x8 X0[4], X1[4];
#pragma unroll
  for (int kt = 0; kt < 4; ++kt)
    X0[kt] = *(const f16x8*)(Abuf + (long)r0 * 128 + kt * 32 + quad * 8);

  int r1 = srow[min(c1 + m15, e1 - 1)];
#pragma unroll
  for (int kt = 0; kt < 4; ++kt) PnN[kt] = PnC[kt];
  if (n1 != n0 && n1 < nEnd) {
#pragma unroll
    for (int kt = 0; kt < 4; ++kt)
      PnN[kt] = *(const f16x8*)(Pbuf + (long)n1 * 128 + kt * 32 + quad * 8);
  }

  int n2 = n1, c2 = c1, e2 = e1;
  adv(n2, c2, e2);
  int r2 = srow[min(c2 + m15, e2 - 1)];

  float runmax[8];
#pragma unroll
  for (int nt = 0; nt < 8; ++nt) runmax[nt] = -3.4e38f;

  auto gatherX = [&](f16x8 (&X)[4], int row) {
#pragma unroll
    for (int kt = 0; kt < 4; ++kt)
      X[kt] = *(const f16x8*)(Abuf + (long)row * 128 + kt * 32 + quad * 8);
  };

  auto computeX = [&](f16x8 (&X)[4]) {
#pragma unroll
    for (int kt = 0; kt < 4; ++kt) X[kt] = sub_relu8(X[kt], PnC[kt]);
#pragma unroll
    for (int half = 0; half < 2; ++half) {
      f32x4 a0 = (f32x4){0.f, 0.f, 0.f, 0.f}, a1 = a0, a2 = a0, a3 = a0;
#pragma unroll
      for (int kt = 0; kt < 4; ++kt) {
        a0 = __builtin_amdgcn_mfma_f32_16x16x32_f16(
            X[kt], *(const f16x8*)&w2s[half * 4 + 0][kt][lane][0], a0, 0, 0, 0);
        a1 = __builtin_amdgcn_mfma_f32_16x16x32_f16(
            X[kt], *(const f16x8*)&w2s[half * 4 + 1][kt][lane][0], a1, 0, 0, 0);
        a2 = __builtin_amdgcn_mfma_f32_16x16x32_f16(
            X[kt], *(const f16x8*)&w2s[half * 4 + 2][kt][lane][0], a2, 0, 0, 0);
        a3 = __builtin_amdgcn_mfma_f32_16x16x32_f16(
            X[kt], *(const f16x8*)&w2s[half * 4 + 3][kt][lane][0], a3, 0, 0, 0);
      }
      runmax[half * 4 + 0] = fmaxf(runmax[half * 4 + 0],
          fmaxf(fmaxf(a0[0], a0[1]), fmaxf(a0[2], a0[3])));
      runmax[half * 4 + 1] = fmaxf(runmax[half * 4 + 1],
          fmaxf(fmaxf(a1[0], a1[1]), fmaxf(a1[2], a1[3])));
      runmax[half * 4 + 2] = fmaxf(runmax[half * 4 + 2],
          fmaxf(fmaxf(a2[0], a2[1]), fmaxf(a2[2], a2[3])));
      runmax[half * 4 + 3] = fmaxf(runmax[half * 4 + 3],
          fmaxf(fmaxf(a3[0], a3[1]), fmaxf(a3[2], a3[3])));
    }
  };

  auto stepRotate = [&]() -> bool {
    if (n1 != n0) {
#pragma unroll
      for (int nt = 0; nt < 8; ++nt) {
        float v = runmax[nt];
        v = fmaxf(v, __shfl_xor(v, 16, 64));
        v = fmaxf(v, __shfl_xor(v, 32, 64));
        v += b2s[nt * 16 + m15];
        if (quad == 0) maxbf[(long)n0 * 128 + nt * 16 + m15] = (f16_t)v;
        runmax[nt] = -3.4e38f;
      }
#pragma unroll
      for (int kt = 0; kt < 4; ++kt) PnC[kt] = PnN[kt];
    }
    n0 = n1; c0 = c1; e0 = e1;
    if (n0 >= nEnd) return true;
    n1 = n2; c1 = c2; e1 = e2; r1 = r2;
    if (n1 != n0 && n1 < nEnd) {
#pragma unroll
      for (int kt = 0; kt < 4; ++kt)
        PnN[kt] = *(const f16x8*)(Pbuf + (long)n1 * 128 + kt * 32 + quad * 8);
    }
    adv(n2, c2, e2);
    r2 = srow[min(c2 + m15, e2 - 1)];
    return false;
  };

  for (;;) {
    // step A: gather next chunk into X1, compute X0
    gatherX(X1, r1);
    computeX(X0);
    if (stepRotate()) break;
    // step B: gather next chunk into X0, compute X1
    gatherX(X0, r1);
    computeX(X1);
    if (stepRotate()) break;
  }
}

// ---------------------------------------------------------------------------
// final (full): d_out = maxbf + x @ Wr + br   (f32 out) — fallback path.
// ---------------------------------------------------------------------------
__global__ __launch_bounds__(256) void final_gemm_kernel(
    const float* __restrict__ xin, const float* __restrict__ W,
    const float* __restrict__ bias, const f16_t* __restrict__ maxv,
    float* __restrict__ dst, int N)
{
  __shared__ f16_t ws_[8][4][64][8];
  __shared__ float bs_[128];

  const int tid = threadIdx.x;
  for (int it = tid; it < 8 * 4 * 64; it += 256) {
    int nt = it >> 8, kt = (it >> 6) & 3, l = it & 63;
    int n = nt * 16 + (l & 15), quad = l >> 4;
    f16x8 v;
#pragma unroll
    for (int j = 0; j < 8; ++j) v[j] = (f16_t)W[(kt * 32 + quad * 8 + j) * 128 + n];
    *(f16x8*)&ws_[nt][kt][l][0] = v;
  }
  if (tid < 128) bs_[tid] = bias[tid];
  __syncthreads();

  const int w = tid >> 6, lane = tid & 63;
  const int m15 = lane & 15, quad = lane >> 4;

  int node_a = blockIdx.x * 64 + w * 16 + m15;
  const float* xrow = xin + (long)min(node_a, N - 1) * 128;
  f16x8 a[4];
#pragma unroll
  for (int kt = 0; kt < 4; ++kt)
    a[kt] = load_frag8h(xrow + kt * 32 + quad * 8);

  f32x4 acc[8];
#pragma unroll
  for (int nt = 0; nt < 8; ++nt) acc[nt] = (f32x4){0.f, 0.f, 0.f, 0.f};
#pragma unroll
  for (int nt = 0; nt < 8; ++nt)
#pragma unroll
    for (int kt = 0; kt < 4; ++kt)
      acc[nt] = __builtin_amdgcn_mfma_f32_16x16x32_f16(
          a[kt], *(const f16x8*)&ws_[nt][kt][lane][0], acc[nt], 0, 0, 0);

#pragma unroll
  for (int r = 0; r < 4; ++r) {
    int node = blockIdx.x * 64 + w * 16 + quad * 4 + r;
    if (node < N) {
#pragma unroll
      for (int nt = 0; nt < 8; ++nt) {
        int c = nt * 16 + m15;
        long idx = (long)node * 128 + c;
        dst[idx] = acc[nt][r] + bs_[c] + (float)maxv[idx];
      }
    }
  }
}

// ---------------------------------------------------------------------------
// final (thin): d_out = Rbuf + maxbf — used when fusedA computed R.
// ---------------------------------------------------------------------------
__global__ __launch_bounds__(256) void final_add_kernel(
    const float* __restrict__ R, const f16_t* __restrict__ maxv,
    float* __restrict__ dst, long total)
{
  long i = ((long)blockIdx.x * 256 + threadIdx.x) * 4;
  const long stride = (long)gridDim.x * 1024;
  for (; i < total; i += stride) {
    float4 r = *(const float4*)(R + i);
    f16x4 m = *(const f16x4*)(maxv + i);
    float4 o;
    o.x = r.x + (float)m[0];
    o.y = r.y + (float)m[1];
    o.z = r.z + (float)m[2];
    o.w = r.w + (float)m[3];
    *(float4*)(dst + i) = o;
  }
}

extern "C" void kernel_launch(void* const* d_in, const int* in_sizes, int n_in,
                              void* d_out, int out_size, void* d_ws, size_t ws_size,
                              hipStream_t stream) {
  (void)n_in; (void)out_size;
  const float* x   = (const float*)d_in[0];
  const float* pos = (const float*)d_in[1];
  const int*   eix = (const int*)d_in[2];
  const float* W1  = (const float*)d_in[3];
  const float* b1  = (const float*)d_in[4];
  const float* W2  = (const float*)d_in[5];
  const float* b2  = (const float*)d_in[6];
  const float* Wr  = (const float*)d_in[7];
  const float* br  = (const float*)d_in[8];

  const int N = in_sizes[0] / 128;
  const int E = in_sizes[2] / 2;

  f16_t* Abuf = (f16_t*)d_out;                      // [0, N*128) f16
  f16_t* Pbuf = (f16_t*)d_out + (size_t)N * 128;    // [N*128, N*256) f16

  const int nodeBlocks = (N + 63) / 64;
  const int edgeBlocks = (E + 255) / 256;
  const int nTiles     = (N + 255) / 256;
  const int NSB        = (N + 255) >> NSB_SHIFT;
  const int paBlocks   = (E + PA_TILE - 1) / PA_TILE;

  f16_t* maxbf = (f16_t*)d_ws;                      // N*256 B

  // packed path ws: maxbf + pairsA + srow + start/end + superCursor [+ Rbuf]
  const size_t needPack = (size_t)N * 256 + (size_t)NSB * SBCAP * 8 +
                          (size_t)N * 8 + (size_t)NSB * 64 + 1024;
  const size_t needR = needPack + (size_t)N * 512;

  if (ws_size >= needPack && NSB <= 256 && N < (1 << 24)) {
    // ---------------- u32-bucketed CSR path ----------------
    unsigned* pairsA      = (unsigned*)((char*)d_ws + (size_t)N * 256);
    int*      srowN       = (int*)(pairsA + (size_t)NSB * SBCAP);
    int*      startB      = (int*)(srowN + (size_t)NSB * SBCAP);
    int*      endB        = startB + N;
    int*      superCursor = endB + N;
    const bool useR = (ws_size >= needR);
    float*    Rbuf = useR ? (float*)((char*)superCursor + (size_t)NSB * 64)
                          : nullptr;

    hipMemsetAsync(superCursor, 0, (size_t)NSB * 64, stream);
    fusedA_kernel<<<nodeBlocks + paBlocks, 256, 0, stream>>>(
        x, pos, eix, W1, b1, Wr, br, pairsA, superCursor, Abuf, Pbuf, Rbuf,
        N, E, nodeBlocks);
    passb_kernel<<<NSB, 256, 0, stream>>>(pairsA, superCursor, srowN,
                                          startB, endB, N);
    pernode_kernel<<<2048, 256, 0, stream>>>(Abuf, Pbuf, W2, b2, startB, endB,
                                             srowN, maxbf, N);
    if (useR)
      final_add_kernel<<<2048, 256, 0, stream>>>(Rbuf, maxbf, (float*)d_out,
                                                 (long)N * 128);
    else
      final_gemm_kernel<<<nodeBlocks, 256, 0, stream>>>(x, Wr, br, maxbf,
                                                        (float*)d_out, N);
  } else {
    // ---------------- fallback: r7 hist+scan+scatter ----------------
    int* srow  = (int*)((char*)d_ws + (size_t)N * 256);
    int* dpad  = srow + E;
    int* start = dpad + (size_t)N * DPAD;
    int* tsum  = start + N + 1;
    int* texcl = tsum + 256;

    hipMemsetAsync(dpad, 0, (size_t)N * DPAD * 4, stream);
    fused_hist_kernel<<<nodeBlocks + edgeBlocks, 256, 0, stream>>>(
        x, pos, eix, W1, b1, dpad, Abuf, Pbuf, N, E, nodeBlocks);
    tilesum_kernel<<<nTiles, 256, 0, stream>>>(dpad, tsum, N);
    tscan_kernel<<<1, 256, 0, stream>>>(tsum, texcl, &start[N], nTiles);
    scanout_kernel<<<nTiles, 256, 0, stream>>>(dpad, texcl, start, N);
    scatter_kernel<<<edgeBlocks, 256, 0, stream>>>(eix, dpad, srow, E);
    pernode_kernel<<<2048, 256, 0, stream>>>(Abuf, Pbuf, W2, b2, start, start + 1,
                                             srow, maxbf, N);
    final_gemm_kernel<<<nodeBlocks, 256, 0, stream>>>(x, Wr, br, maxbf,
                                                      (float*)d_out, N);
  }
}

// Round 9
// 277.228 us; speedup vs baseline: 1.1959x; 1.0292x over previous
//
#include <hip/hip_runtime.h>
#include <hip/hip_bf16.h>

// PointNetConv on MI355X (gfx950) — round 16. f32 inputs.
// Algebra: h1 = relu(A[row] - P[col]),  A = x@W1x + b1 + pos@W1p,  P = pos@W1p.
//
// r15 post-mortem: ping-pong unroll REGRESSED pernode 131->151 (same VGPR/occ;
// VALU fell 45->36 but schedule worsened — 3rd structural perturbation to
// lose). r13's 3-level stream is a local optimum: keep it EXACTLY.
// Wr-fusion was neutral (kept). Non-pernode time ~134us is fusedA-dominated.
//
// r16: (1) pernode = r13-exact body. (2) fusedA: 128 nodes/GEMM-block
// (halves W1+Wr staging overhead per node), PA_TILE 4096 (halves passA
// per-tile overhead), passA scan 16-barrier Hillis-Steele -> 2-barrier
// wave-scan (proven tscan pattern).

typedef _Float16 f16_t;
typedef _Float16 f16x8 __attribute__((ext_vector_type(8)));
typedef _Float16 f16x4 __attribute__((ext_vector_type(4)));
typedef float    f32x4 __attribute__((ext_vector_type(4)));

#define DPAD 16
#define NSB_SHIFT 8          // 256 nodes per superbucket
#define SBCAP 9216           // per-bucket edge cap (mean 8192, +11 sigma)
#define PA_TILE 4096         // edges per passA tile

__device__ __forceinline__ f16x8 sub_relu8(f16x8 a, f16x8 b) {
  f16x8 d = a - b;                          // v_pk_add_f16 (neg)
  f16x8 z = {};
  return __builtin_elementwise_max(d, z);   // v_pk_max_f16
}

// ---------------- fallback scan chain (proven r7) ----------------
__global__ __launch_bounds__(256) void tilesum_kernel(const int* __restrict__ dpad,
                                                      int* __restrict__ tsum, int N) {
  __shared__ int ws[4];
  int tid = threadIdx.x;
  int i = blockIdx.x * 256 + tid;
  int v = (i < N) ? dpad[(long)i * DPAD] : 0;
#pragma unroll
  for (int off = 32; off > 0; off >>= 1) v += __shfl_down(v, off, 64);
  if ((tid & 63) == 0) ws[tid >> 6] = v;
  __syncthreads();
  if (tid == 0) tsum[blockIdx.x] = ws[0] + ws[1] + ws[2] + ws[3];
}

__global__ __launch_bounds__(256) void tscan_kernel(const int* __restrict__ tsum,
                                                    int* __restrict__ texcl,
                                                    int* __restrict__ startN, int nt_) {
  __shared__ int wsum[4];
  int tid = threadIdx.x, lane = tid & 63, w = tid >> 6;
  int v = (tid < nt_) ? tsum[tid] : 0;
  int s = v;
#pragma unroll
  for (int off = 1; off < 64; off <<= 1) {
    int t = __shfl_up(s, off, 64);
    if (lane >= off) s += t;
  }
  if (lane == 63) wsum[w] = s;
  __syncthreads();
  int add = 0;
  for (int j = 0; j < w; ++j) add += wsum[j];
  if (tid < nt_) texcl[tid] = add + s - v;
  if (tid == 0) *startN = wsum[0] + wsum[1] + wsum[2] + wsum[3];
}

__global__ __launch_bounds__(256) void scanout_kernel(int* __restrict__ dpad,
                                                      const int* __restrict__ texcl,
                                                      int* __restrict__ start, int N) {
  __shared__ int wsum[4];
  int tid = threadIdx.x, lane = tid & 63, w = tid >> 6;
  int i = blockIdx.x * 256 + tid;
  int v = (i < N) ? dpad[(long)i * DPAD] : 0;
  int s = v;
#pragma unroll
  for (int off = 1; off < 64; off <<= 1) {
    int t = __shfl_up(s, off, 64);
    if (lane >= off) s += t;
  }
  if (lane == 63) wsum[w] = s;
  __syncthreads();
  int add = texcl[blockIdx.x];
  for (int j = 0; j < w; ++j) add += wsum[j];
  int excl = add + s - v;
  if (i < N) { start[i] = excl; dpad[(long)i * DPAD + 8] = excl; }
}

__global__ __launch_bounds__(256) void scatter_kernel(const int* __restrict__ eidx,
                                                      int* __restrict__ dpad,
                                                      int* __restrict__ srow, int E) {
  int i = blockIdx.x * 256 + threadIdx.x;
  if (i < E) {
    int slot = atomicAdd(&dpad[(long)eidx[E + i] * DPAD + 8], 1);
    srow[slot] = eidx[i];
  }
}

__device__ __forceinline__ f16x8 load_frag8h(const float* p) {
  float4 a = *(const float4*)p;
  float4 b = *(const float4*)(p + 4);
  f16x8 r;
  r[0] = (f16_t)a.x; r[1] = (f16_t)a.y; r[2] = (f16_t)a.z; r[3] = (f16_t)a.w;
  r[4] = (f16_t)b.x; r[5] = (f16_t)b.y; r[6] = (f16_t)b.z; r[7] = (f16_t)b.w;
  return r;
}

// ---------------------------------------------------------------------------
// Shared-memory structs for the role-split kernels (union via char buffer).
// ---------------------------------------------------------------------------
struct GemmSmem {
  f16_t ws_[8][4][64][8];    // 32768 B
  float w1ps[3][128];        //  1536 B
  float bs_[128];            //   512 B
  float brs[128];            //   512 B
  float pos_s[128][3];       //  1536 B
};                           // 36864 B

struct PassASmem {
  unsigned sorted[PA_TILE];       // 16384 B
  unsigned char sbb[PA_TILE];     //  4096 B
  int hist[256];
  int off_[256];
  int cur[256];
  int gbase[256];
  int wtot[4];
};                                // ~24.6 KB

#define SMEM_BYTES 36864

// ---------------------------------------------------------------------------
// AP-GEMM body: 128 nodes/block. A = x@W1x + b1 + pos@W1p, P = pos@W1p.
// If Rbuf != null: restage ws_ with Wr and also emit R = x@Wr + br (f32).
// ---------------------------------------------------------------------------
__device__ __forceinline__ void ap_gemm_body(
    const float* __restrict__ x, const float* __restrict__ pos,
    const float* __restrict__ W1, const float* __restrict__ b1,
    const float* __restrict__ Wr, const float* __restrict__ br_,
    f16_t* __restrict__ Abuf, f16_t* __restrict__ Pbuf,
    float* __restrict__ Rbuf, int N, int blk, char* smem)
{
  GemmSmem* G = (GemmSmem*)smem;
  const int tid = threadIdx.x;
  for (int it = tid; it < 8 * 4 * 64; it += 256) {
    int nt = it >> 8, kt = (it >> 6) & 3, l = it & 63;
    int n = nt * 16 + (l & 15), quad = l >> 4;
    f16x8 v;
#pragma unroll
    for (int j = 0; j < 8; ++j) v[j] = (f16_t)W1[(kt * 32 + quad * 8 + j) * 128 + n];
    *(f16x8*)&G->ws_[nt][kt][l][0] = v;
  }
  for (int it = tid; it < 384; it += 256)
    G->w1ps[it >> 7][it & 127] = W1[(128 + (it >> 7)) * 128 + (it & 127)];
  if (tid < 128) G->bs_[tid] = b1[tid];
  for (int it = tid; it < 384; it += 256) {
    int g = blk * 384 + it;
    if (g < 3 * N) G->pos_s[it / 3][it % 3] = pos[g];
  }
  __syncthreads();

  const int w = tid >> 6, lane = tid & 63;
  const int m15 = lane & 15, quad = lane >> 4;

  // a-fragments for both 64-node groups (kept live across W1 and Wr phases)
  const int nodeA = blk * 128 + w * 16 + m15;
  const int nodeB = nodeA + 64;
  const float* xr0 = x + (long)min(nodeA, N - 1) * 128;
  const float* xr1 = x + (long)min(nodeB, N - 1) * 128;
  f16x8 a0[4], a1[4];
#pragma unroll
  for (int kt = 0; kt < 4; ++kt) {
    a0[kt] = load_frag8h(xr0 + kt * 32 + quad * 8);
    a1[kt] = load_frag8h(xr1 + kt * 32 + quad * 8);
  }

#pragma unroll
  for (int g = 0; g < 2; ++g) {
    f32x4 acc[8];
#pragma unroll
    for (int nt = 0; nt < 8; ++nt) acc[nt] = (f32x4){0.f, 0.f, 0.f, 0.f};
#pragma unroll
    for (int nt = 0; nt < 8; ++nt)
#pragma unroll
      for (int kt = 0; kt < 4; ++kt)
        acc[nt] = __builtin_amdgcn_mfma_f32_16x16x32_f16(
            g == 0 ? a0[kt] : a1[kt],
            *(const f16x8*)&G->ws_[nt][kt][lane][0], acc[nt], 0, 0, 0);

#pragma unroll
    for (int r = 0; r < 4; ++r) {
      int nl = g * 64 + w * 16 + quad * 4 + r;
      int node = blk * 128 + nl;
      if (node < N) {
        float p0 = G->pos_s[nl][0], p1 = G->pos_s[nl][1], p2 = G->pos_s[nl][2];
#pragma unroll
        for (int nt = 0; nt < 8; ++nt) {
          int c = nt * 16 + m15;
          float pv = p0 * G->w1ps[0][c] + p1 * G->w1ps[1][c] + p2 * G->w1ps[2][c];
          long idx = (long)node * 128 + c;
          Abuf[idx] = (f16_t)(acc[nt][r] + G->bs_[c] + pv);
          Pbuf[idx] = (f16_t)pv;
        }
      }
    }
  }

  if (Rbuf) {
    __syncthreads();                         // all waves done reading ws_ (W1)
    for (int it = tid; it < 8 * 4 * 64; it += 256) {
      int nt = it >> 8, kt = (it >> 6) & 3, l = it & 63;
      int n = nt * 16 + (l & 15), q = l >> 4;
      f16x8 v;
#pragma unroll
      for (int j = 0; j < 8; ++j) v[j] = (f16_t)Wr[(kt * 32 + q * 8 + j) * 128 + n];
      *(f16x8*)&G->ws_[nt][kt][l][0] = v;
    }
    if (tid < 128) G->brs[tid] = br_[tid];
    __syncthreads();

#pragma unroll
    for (int g = 0; g < 2; ++g) {
      f32x4 acc2[8];
#pragma unroll
      for (int nt = 0; nt < 8; ++nt) acc2[nt] = (f32x4){0.f, 0.f, 0.f, 0.f};
#pragma unroll
      for (int nt = 0; nt < 8; ++nt)
#pragma unroll
        for (int kt = 0; kt < 4; ++kt)
          acc2[nt] = __builtin_amdgcn_mfma_f32_16x16x32_f16(
              g == 0 ? a0[kt] : a1[kt],
              *(const f16x8*)&G->ws_[nt][kt][lane][0], acc2[nt], 0, 0, 0);

#pragma unroll
      for (int r = 0; r < 4; ++r) {
        int node = blk * 128 + g * 64 + w * 16 + quad * 4 + r;
        if (node < N) {
#pragma unroll
          for (int nt = 0; nt < 8; ++nt) {
            int c = nt * 16 + m15;
            Rbuf[(long)node * 128 + c] = acc2[nt][r] + G->brs[c];
          }
        }
      }
    }
  }
}

// ---------------------------------------------------------------------------
// passA body: tile-sort PA_TILE edges into superbuckets, all random ops in
// LDS; ~NSB aggregated global atomics per tile; coalesced u32 segment writes.
// Entry format: (col&255)<<24 | row. Scan = 2-barrier wave-scan.
// ---------------------------------------------------------------------------
__device__ __forceinline__ void passa_body(
    const int* __restrict__ eidx, unsigned* __restrict__ pairsBuf,
    int* __restrict__ superCursor, int E, int tile, char* smem)
{
  PassASmem* S = (PassASmem*)smem;
  const int tid = threadIdx.x;
  const int lane = tid & 63, w = tid >> 6;
  const int base = tile * PA_TILE;
  const int cnt_t = min(PA_TILE, E - base);

  S->hist[tid] = 0;
  __syncthreads();

  int myrow[16], mycol[16];
#pragma unroll
  for (int k = 0; k < 16; ++k) {
    int idx = k * 256 + tid;
    int i = base + idx;
    if (idx < cnt_t) {
      myrow[k] = eidx[i];
      mycol[k] = eidx[E + i];
      atomicAdd(&S->hist[mycol[k] >> NSB_SHIFT], 1);
    } else mycol[k] = -1;
  }
  __syncthreads();

  // 2-barrier wave-cooperative exclusive scan over 256 bins
  int v = S->hist[tid];
  int s = v;
#pragma unroll
  for (int off = 1; off < 64; off <<= 1) {
    int t = __shfl_up(s, off, 64);
    if (lane >= off) s += t;
  }
  if (lane == 63) S->wtot[w] = s;
  __syncthreads();
  int add = 0;
  for (int j = 0; j < w; ++j) add += S->wtot[j];
  int excl = add + s - v;
  S->off_[tid] = excl;
  S->cur[tid]  = excl;
  S->gbase[tid] = (v > 0) ? atomicAdd(&superCursor[tid * 16], v) : 0;
  __syncthreads();

#pragma unroll
  for (int k = 0; k < 16; ++k) {
    if (mycol[k] >= 0) {
      int sb = mycol[k] >> NSB_SHIFT;
      int pos = atomicAdd(&S->cur[sb], 1);
      S->sorted[pos] = ((unsigned)(mycol[k] & 255) << 24) | (unsigned)myrow[k];
      S->sbb[pos] = (unsigned char)sb;
    }
  }
  __syncthreads();

#pragma unroll
  for (int k = 0; k < 16; ++k) {
    int idx = k * 256 + tid;
    if (idx < cnt_t) {
      int sb = S->sbb[idx];
      int local = idx - S->off_[sb];
      int g = S->gbase[sb] + local;
      if (g < SBCAP) pairsBuf[(long)sb * SBCAP + g] = S->sorted[idx];
    }
  }
}

// fusedA: AP-GEMM role (128 nodes/block) + passA role in one launch.
__global__ __launch_bounds__(256) void fusedA_kernel(
    const float* __restrict__ x, const float* __restrict__ pos,
    const int* __restrict__ eidx, const float* __restrict__ W1,
    const float* __restrict__ b1, const float* __restrict__ Wr,
    const float* __restrict__ br_, unsigned* __restrict__ pairsBuf,
    int* __restrict__ superCursor, f16_t* __restrict__ Abuf,
    f16_t* __restrict__ Pbuf, float* __restrict__ Rbuf,
    int N, int E, int nodeBlocks)
{
  __shared__ __align__(16) char smem[SMEM_BYTES];
  if ((int)blockIdx.x >= nodeBlocks) {
    passa_body(eidx, pairsBuf, superCursor, E, (int)blockIdx.x - nodeBlocks, smem);
    return;
  }
  ap_gemm_body(x, pos, W1, b1, Wr, br_, Abuf, Pbuf, Rbuf, N, blockIdx.x, smem);
}

// Fallback path: hist role + AP-GEMM role (r7-proven).
__global__ __launch_bounds__(256) void fused_hist_kernel(
    const float* __restrict__ x, const float* __restrict__ pos,
    const int* __restrict__ eidx, const float* __restrict__ W1,
    const float* __restrict__ b1, int* __restrict__ dpad,
    f16_t* __restrict__ Abuf, f16_t* __restrict__ Pbuf,
    int N, int E, int nodeBlocks)
{
  __shared__ __align__(16) char smem[SMEM_BYTES];
  if ((int)blockIdx.x >= nodeBlocks) {
    int i = ((int)blockIdx.x - nodeBlocks) * 256 + threadIdx.x;
    if (i < E) atomicAdd(&dpad[(long)eidx[E + i] * DPAD], 1);
    return;
  }
  ap_gemm_body(x, pos, W1, b1, nullptr, nullptr, Abuf, Pbuf, nullptr, N,
               blockIdx.x, smem);
}

// ---------------------------------------------------------------------------
// passB: one block per superbucket; exact per-node CSR built in LDS from u32
// pairs. Emits r10-format CSR: srow (row indices), startB[n], endB[n].
// ---------------------------------------------------------------------------
__global__ __launch_bounds__(256) void passb_kernel(
    const unsigned* __restrict__ pairsA, const int* __restrict__ superCursor,
    int* __restrict__ srow, int* __restrict__ startB, int* __restrict__ endB,
    int N)
{
  __shared__ int rows[SBCAP];     // 36 KB
  __shared__ int deg[256], scanb[256], cur[256];
  const int sb = blockIdx.x, tid = threadIdx.x;
  const int cntIn = min(superCursor[sb * 16], SBCAP);
  const unsigned* Pin = pairsA + (long)sb * SBCAP;

  deg[tid] = 0;
  __syncthreads();
  for (int i = tid; i < cntIn; i += 256)
    atomicAdd(&deg[Pin[i] >> 24], 1);
  __syncthreads();
  int d = deg[tid];
  scanb[tid] = d;
  __syncthreads();
  for (int s = 1; s < 256; s <<= 1) {
    int t2 = (tid >= s) ? scanb[tid - s] : 0;
    __syncthreads();
    scanb[tid] += t2;
    __syncthreads();
  }
  int excl = scanb[tid] - d;
  cur[tid] = excl;
  int n = (sb << NSB_SHIFT) + tid;
  if (n < N) {
    startB[n] = sb * SBCAP + excl;
    endB[n]   = sb * SBCAP + excl + d;
  }
  __syncthreads();
  for (int i = tid; i < cntIn; i += 256) {
    unsigned p = Pin[i];
    int slot = atomicAdd(&cur[p >> 24], 1);
    rows[slot] = (int)(p & 0xFFFFFFu);
  }
  __syncthreads();
  const int gb = sb * SBCAP;
  for (int i = tid; i < cntIn; i += 256) srow[gb + i] = rows[i];
}

// ---------------------------------------------------------------------------
// pernode (r13-EXACT, proven 131us): continuous (node,chunk) stream per wave;
// 3-level pipeline crossing node boundaries (srow 2 ahead, A-gather +
// next-node P 1 ahead, compute level-0). Do not perturb (r14/r15 both lost).
// ---------------------------------------------------------------------------
__global__ __launch_bounds__(256) void pernode_kernel(
    const f16_t* __restrict__ Abuf, const f16_t* __restrict__ Pbuf,
    const float* __restrict__ W2, const float* __restrict__ b2,
    const int* __restrict__ startp, const int* __restrict__ endp,
    const int* __restrict__ srow, f16_t* __restrict__ maxbf, int N)
{
  __shared__ f16_t w2s[8][4][64][8];   // 32 KB, B-fragment-major
  __shared__ float b2s[128];

  const int tid = threadIdx.x;
  for (int it = tid; it < 8 * 4 * 64; it += 256) {
    int nt = it >> 8, kt = (it >> 6) & 3, l = it & 63;
    int ncol = nt * 16 + (l & 15), q = l >> 4;
    f16x8 v;
#pragma unroll
    for (int j = 0; j < 8; ++j) v[j] = (f16_t)W2[(kt * 32 + q * 8 + j) * 128 + ncol];
    *(f16x8*)&w2s[nt][kt][l][0] = v;
  }
  if (tid < 128) b2s[tid] = b2[tid];
  __syncthreads();

  const int w = tid >> 6, lane = tid & 63;
  const int m15 = lane & 15, quad = lane >> 4;

  const int nslots = (int)gridDim.x * 4;
  const int slot   = (int)blockIdx.x * 4 + w;
  const int K      = (N + nslots - 1) / nslots;
  const int nBeg   = slot * K;
  const int nEnd   = min(N, nBeg + K);
  if (nBeg >= nEnd) return;

  auto adv = [&](int& n, int& c, int& e) {
    c += 16;
    if (c < e) return;
    for (;;) {
      if (++n >= nEnd) { n = nEnd; c -= 16; return; }
      int s_ = startp[n], e_ = endp[n];
      if (e_ > s_) { c = s_; e = e_; return; }
      if (quad == 0) {
#pragma unroll
        for (int nt = 0; nt < 8; ++nt)
          maxbf[(long)n * 128 + nt * 16 + m15] = (f16_t)0.f;
      }
    }
  };

  int n0 = nBeg - 1, c0 = -16, e0 = 0;
  adv(n0, c0, e0);
  if (n0 >= nEnd) return;

  f16x8 PnC[4], PnN[4];
#pragma unroll
  for (int kt = 0; kt < 4; ++kt)
    PnC[kt] = *(const f16x8*)(Pbuf + (long)n0 * 128 + kt * 32 + quad * 8);
  int r0 = srow[min(c0 + m15, e0 - 1)];

  int n1 = n0, c1 = c0, e1 = e0;
  adv(n1, c1, e1);

  f16x8 xv[4];
#pragma unroll
  for (int kt = 0; kt < 4; ++kt)
    xv[kt] = *(const f16x8*)(Abuf + (long)r0 * 128 + kt * 32 + quad * 8);

  int r1 = srow[min(c1 + m15, e1 - 1)];
#pragma unroll
  for (int kt = 0; kt < 4; ++kt) PnN[kt] = PnC[kt];
  if (n1 != n0 && n1 < nEnd) {
#pragma unroll
    for (int kt = 0; kt < 4; ++kt)
      PnN[kt] = *(const f16x8*)(Pbuf + (long)n1 * 128 + kt * 32 + quad * 8);
  }

  int n2 = n1, c2 = c1, e2 = e1;
  adv(n2, c2, e2);
  int r2 = srow[min(c2 + m15, e2 - 1)];

  float runmax[8];
#pragma unroll
  for (int nt = 0; nt < 8; ++nt) runmax[nt] = -3.4e38f;

  for (;;) {
    f16x8 xn[4];
#pragma unroll
    for (int kt = 0; kt < 4; ++kt)
      xn[kt] = *(const f16x8*)(Abuf + (long)r1 * 128 + kt * 32 + quad * 8);

#pragma unroll
    for (int kt = 0; kt < 4; ++kt) xv[kt] = sub_relu8(xv[kt], PnC[kt]);

#pragma unroll
    for (int half = 0; half < 2; ++half) {
      f32x4 a0 = (f32x4){0.f, 0.f, 0.f, 0.f}, a1 = a0, a2 = a0, a3 = a0;
#pragma unroll
      for (int kt = 0; kt < 4; ++kt) {
        a0 = __builtin_amdgcn_mfma_f32_16x16x32_f16(
            xv[kt], *(const f16x8*)&w2s[half * 4 + 0][kt][lane][0], a0, 0, 0, 0);
        a1 = __builtin_amdgcn_mfma_f32_16x16x32_f16(
            xv[kt], *(const f16x8*)&w2s[half * 4 + 1][kt][lane][0], a1, 0, 0, 0);
        a2 = __builtin_amdgcn_mfma_f32_16x16x32_f16(
            xv[kt], *(const f16x8*)&w2s[half * 4 + 2][kt][lane][0], a2, 0, 0, 0);
        a3 = __builtin_amdgcn_mfma_f32_16x16x32_f16(
            xv[kt], *(const f16x8*)&w2s[half * 4 + 3][kt][lane][0], a3, 0, 0, 0);
      }
      runmax[half * 4 + 0] = fmaxf(runmax[half * 4 + 0],
          fmaxf(fmaxf(a0[0], a0[1]), fmaxf(a0[2], a0[3])));
      runmax[half * 4 + 1] = fmaxf(runmax[half * 4 + 1],
          fmaxf(fmaxf(a1[0], a1[1]), fmaxf(a1[2], a1[3])));
      runmax[half * 4 + 2] = fmaxf(runmax[half * 4 + 2],
          fmaxf(fmaxf(a2[0], a2[1]), fmaxf(a2[2], a2[3])));
      runmax[half * 4 + 3] = fmaxf(runmax[half * 4 + 3],
          fmaxf(fmaxf(a3[0], a3[1]), fmaxf(a3[2], a3[3])));
    }

    if (n1 != n0) {
#pragma unroll
      for (int nt = 0; nt < 8; ++nt) {
        float v = runmax[nt];
        v = fmaxf(v, __shfl_xor(v, 16, 64));
        v = fmaxf(v, __shfl_xor(v, 32, 64));
        v += b2s[nt * 16 + m15];
        if (quad == 0) maxbf[(long)n0 * 128 + nt * 16 + m15] = (f16_t)v;
        runmax[nt] = -3.4e38f;
      }
#pragma unroll
      for (int kt = 0; kt < 4; ++kt) PnC[kt] = PnN[kt];
    }

    n0 = n1; c0 = c1; e0 = e1;
    if (n0 >= nEnd) break;
#pragma unroll
    for (int kt = 0; kt < 4; ++kt) xv[kt] = xn[kt];

    n1 = n2; c1 = c2; e1 = e2; r1 = r2;
    if (n1 != n0 && n1 < nEnd) {
#pragma unroll
      for (int kt = 0; kt < 4; ++kt)
        PnN[kt] = *(const f16x8*)(Pbuf + (long)n1 * 128 + kt * 32 + quad * 8);
    }

    adv(n2, c2, e2);
    r2 = srow[min(c2 + m15, e2 - 1)];
  }
}

// ---------------------------------------------------------------------------
// final (full): d_out = maxbf + x @ Wr + br   (f32 out) — fallback path.
// ---------------------------------------------------------------------------
__global__ __launch_bounds__(256) void final_gemm_kernel(
    const float* __restrict__ xin, const float* __restrict__ W,
    const float* __restrict__ bias, const f16_t* __restrict__ maxv,
    float* __restrict__ dst, int N)
{
  __shared__ f16_t ws_[8][4][64][8];
  __shared__ float bs_[128];

  const int tid = threadIdx.x;
  for (int it = tid; it < 8 * 4 * 64; it += 256) {
    int nt = it >> 8, kt = (it >> 6) & 3, l = it & 63;
    int n = nt * 16 + (l & 15), quad = l >> 4;
    f16x8 v;
#pragma unroll
    for (int j = 0; j < 8; ++j) v[j] = (f16_t)W[(kt * 32 + quad * 8 + j) * 128 + n];
    *(f16x8*)&ws_[nt][kt][l][0] = v;
  }
  if (tid < 128) bs_[tid] = bias[tid];
  __syncthreads();

  const int w = tid >> 6, lane = tid & 63;
  const int m15 = lane & 15, quad = lane >> 4;

  int node_a = blockIdx.x * 64 + w * 16 + m15;
  const float* xrow = xin + (long)min(node_a, N - 1) * 128;
  f16x8 a[4];
#pragma unroll
  for (int kt = 0; kt < 4; ++kt)
    a[kt] = load_frag8h(xrow + kt * 32 + quad * 8);

  f32x4 acc[8];
#pragma unroll
  for (int nt = 0; nt < 8; ++nt) acc[nt] = (f32x4){0.f, 0.f, 0.f, 0.f};
#pragma unroll
  for (int nt = 0; nt < 8; ++nt)
#pragma unroll
    for (int kt = 0; kt < 4; ++kt)
      acc[nt] = __builtin_amdgcn_mfma_f32_16x16x32_f16(
          a[kt], *(const f16x8*)&ws_[nt][kt][lane][0], acc[nt], 0, 0, 0);

#pragma unroll
  for (int r = 0; r < 4; ++r) {
    int node = blockIdx.x * 64 + w * 16 + quad * 4 + r;
    if (node < N) {
#pragma unroll
      for (int nt = 0; nt < 8; ++nt) {
        int c = nt * 16 + m15;
        long idx = (long)node * 128 + c;
        dst[idx] = acc[nt][r] + bs_[c] + (float)maxv[idx];
      }
    }
  }
}

// ---------------------------------------------------------------------------
// final (thin): d_out = Rbuf + maxbf — used when fusedA computed R.
// ---------------------------------------------------------------------------
__global__ __launch_bounds__(256) void final_add_kernel(
    const float* __restrict__ R, const f16_t* __restrict__ maxv,
    float* __restrict__ dst, long total)
{
  long i = ((long)blockIdx.x * 256 + threadIdx.x) * 4;
  const long stride = (long)gridDim.x * 1024;
  for (; i < total; i += stride) {
    float4 r = *(const float4*)(R + i);
    f16x4 m = *(const f16x4*)(maxv + i);
    float4 o;
    o.x = r.x + (float)m[0];
    o.y = r.y + (float)m[1];
    o.z = r.z + (float)m[2];
    o.w = r.w + (float)m[3];
    *(float4*)(dst + i) = o;
  }
}

extern "C" void kernel_launch(void* const* d_in, const int* in_sizes, int n_in,
                              void* d_out, int out_size, void* d_ws, size_t ws_size,
                              hipStream_t stream) {
  (void)n_in; (void)out_size;
  const float* x   = (const float*)d_in[0];
  const float* pos = (const float*)d_in[1];
  const int*   eix = (const int*)d_in[2];
  const float* W1  = (const float*)d_in[3];
  const float* b1  = (const float*)d_in[4];
  const float* W2  = (const float*)d_in[5];
  const float* b2  = (const float*)d_in[6];
  const float* Wr  = (const float*)d_in[7];
  const float* br  = (const float*)d_in[8];

  const int N = in_sizes[0] / 128;
  const int E = in_sizes[2] / 2;

  f16_t* Abuf = (f16_t*)d_out;                      // [0, N*128) f16
  f16_t* Pbuf = (f16_t*)d_out + (size_t)N * 128;    // [N*128, N*256) f16

  const int nodeBlocks64  = (N + 63) / 64;           // final_gemm grid
  const int nodeBlocks128 = (N + 127) / 128;         // fusedA GEMM role
  const int edgeBlocks = (E + 255) / 256;
  const int nTiles     = (N + 255) / 256;
  const int NSB        = (N + 255) >> NSB_SHIFT;
  const int paBlocks   = (E + PA_TILE - 1) / PA_TILE;

  f16_t* maxbf = (f16_t*)d_ws;                      // N*256 B

  // packed path ws: maxbf + pairsA + srow + start/end + superCursor [+ Rbuf]
  const size_t needPack = (size_t)N * 256 + (size_t)NSB * SBCAP * 8 +
                          (size_t)N * 8 + (size_t)NSB * 64 + 1024;
  const size_t needR = needPack + (size_t)N * 512;

  if (ws_size >= needPack && NSB <= 256 && N < (1 << 24)) {
    // ---------------- u32-bucketed CSR path ----------------
    unsigned* pairsA      = (unsigned*)((char*)d_ws + (size_t)N * 256);
    int*      srowN       = (int*)(pairsA + (size_t)NSB * SBCAP);
    int*      startB      = (int*)(srowN + (size_t)NSB * SBCAP);
    int*      endB        = startB + N;
    int*      superCursor = endB + N;
    const bool useR = (ws_size >= needR);
    float*    Rbuf = useR ? (float*)((char*)superCursor + (size_t)NSB * 64)
                          : nullptr;

    hipMemsetAsync(superCursor, 0, (size_t)NSB * 64, stream);
    fusedA_kernel<<<nodeBlocks128 + paBlocks, 256, 0, stream>>>(
        x, pos, eix, W1, b1, Wr, br, pairsA, superCursor, Abuf, Pbuf, Rbuf,
        N, E, nodeBlocks128);
    passb_kernel<<<NSB, 256, 0, stream>>>(pairsA, superCursor, srowN,
                                          startB, endB, N);
    pernode_kernel<<<2048, 256, 0, stream>>>(Abuf, Pbuf, W2, b2, startB, endB,
                                             srowN, maxbf, N);
    if (useR)
      final_add_kernel<<<2048, 256, 0, stream>>>(Rbuf, maxbf, (float*)d_out,
                                                 (long)N * 128);
    else
      final_gemm_kernel<<<nodeBlocks64, 256, 0, stream>>>(x, Wr, br, maxbf,
                                                          (float*)d_out, N);
  } else {
    // ---------------- fallback: r7 hist+scan+scatter ----------------
    int* srow  = (int*)((char*)d_ws + (size_t)N * 256);
    int* dpad  = srow + E;
    int* start = dpad + (size_t)N * DPAD;
    int* tsum  = start + N + 1;
    int* texcl = tsum + 256;

    hipMemsetAsync(dpad, 0, (size_t)N * DPAD * 4, stream);
    fused_hist_kernel<<<nodeBlocks128 + edgeBlocks, 256, 0, stream>>>(
        x, pos, eix, W1, b1, dpad, Abuf, Pbuf, N, E, nodeBlocks128);
    tilesum_kernel<<<nTiles, 256, 0, stream>>>(dpad, tsum, N);
    tscan_kernel<<<1, 256, 0, stream>>>(tsum, texcl, &start[N], nTiles);
    scanout_kernel<<<nTiles, 256, 0, stream>>>(dpad, texcl, start, N);
    scatter_kernel<<<edgeBlocks, 256, 0, stream>>>(eix, dpad, srow, E);
    pernode_kernel<<<2048, 256, 0, stream>>>(Abuf, Pbuf, W2, b2, start, start + 1,
                                             srow, maxbf, N);
    final_gemm_kernel<<<nodeBlocks64, 256, 0, stream>>>(x, Wr, br, maxbf,
                                                        (float*)d_out, N);
  }
}

// Round 10
// 276.345 us; speedup vs baseline: 1.1998x; 1.0032x over previous
//
#include <hip/hip_runtime.h>
#include <hip/hip_bf16.h>

// PointNetConv on MI355X (gfx950) — round 17. f32 inputs.
// Algebra: h1 = relu(A[row] - P[col]),  A = x@W1x + b1 + pos@W1p,  P = pos@W1p.
//
// r16 post-mortem: pernode r13-body reproduced (129.8us); fusedA changes
// (128-node blocks, PA_TILE 4096, wave-scan) regressed non-pernode 136->147.
// Reverted to r13-exact fusedA/passA/passB/final (measured-best 267.4).
//
// r17: pernode residency lever (first non-schedule change): 512-thread
// blocks, 8 waves share ONE 33KB w2s copy -> LDS/wave halves -> cap 16 ->
// 32 waves/CU. Per-wave body bit-identical to r13 (slot = blockIdx*8+w,
// grid 1024). FETCH*BW ~= duration says gather-latency still dominates;
// doubling residency attacks exactly that.

typedef _Float16 f16_t;
typedef _Float16 f16x8 __attribute__((ext_vector_type(8)));
typedef float    f32x4 __attribute__((ext_vector_type(4)));

#define DPAD 16
#define NSB_SHIFT 8          // 256 nodes per superbucket
#define SBCAP 9216           // per-bucket edge cap (mean 8192, +11 sigma)
#define PA_TILE 2048         // edges per passA tile

__device__ __forceinline__ f16x8 sub_relu8(f16x8 a, f16x8 b) {
  f16x8 d = a - b;                          // v_pk_add_f16 (neg)
  f16x8 z = {};
  return __builtin_elementwise_max(d, z);   // v_pk_max_f16
}

// ---------------- fallback scan chain (proven r7) ----------------
__global__ __launch_bounds__(256) void tilesum_kernel(const int* __restrict__ dpad,
                                                      int* __restrict__ tsum, int N) {
  __shared__ int ws[4];
  int tid = threadIdx.x;
  int i = blockIdx.x * 256 + tid;
  int v = (i < N) ? dpad[(long)i * DPAD] : 0;
#pragma unroll
  for (int off = 32; off > 0; off >>= 1) v += __shfl_down(v, off, 64);
  if ((tid & 63) == 0) ws[tid >> 6] = v;
  __syncthreads();
  if (tid == 0) tsum[blockIdx.x] = ws[0] + ws[1] + ws[2] + ws[3];
}

__global__ __launch_bounds__(256) void tscan_kernel(const int* __restrict__ tsum,
                                                    int* __restrict__ texcl,
                                                    int* __restrict__ startN, int nt_) {
  __shared__ int wsum[4];
  int tid = threadIdx.x, lane = tid & 63, w = tid >> 6;
  int v = (tid < nt_) ? tsum[tid] : 0;
  int s = v;
#pragma unroll
  for (int off = 1; off < 64; off <<= 1) {
    int t = __shfl_up(s, off, 64);
    if (lane >= off) s += t;
  }
  if (lane == 63) wsum[w] = s;
  __syncthreads();
  int add = 0;
  for (int j = 0; j < w; ++j) add += wsum[j];
  if (tid < nt_) texcl[tid] = add + s - v;
  if (tid == 0) *startN = wsum[0] + wsum[1] + wsum[2] + wsum[3];
}

__global__ __launch_bounds__(256) void scanout_kernel(int* __restrict__ dpad,
                                                      const int* __restrict__ texcl,
                                                      int* __restrict__ start, int N) {
  __shared__ int wsum[4];
  int tid = threadIdx.x, lane = tid & 63, w = tid >> 6;
  int i = blockIdx.x * 256 + tid;
  int v = (i < N) ? dpad[(long)i * DPAD] : 0;
  int s = v;
#pragma unroll
  for (int off = 1; off < 64; off <<= 1) {
    int t = __shfl_up(s, off, 64);
    if (lane >= off) s += t;
  }
  if (lane == 63) wsum[w] = s;
  __syncthreads();
  int add = texcl[blockIdx.x];
  for (int j = 0; j < w; ++j) add += wsum[j];
  int excl = add + s - v;
  if (i < N) { start[i] = excl; dpad[(long)i * DPAD + 8] = excl; }
}

__global__ __launch_bounds__(256) void scatter_kernel(const int* __restrict__ eidx,
                                                      int* __restrict__ dpad,
                                                      int* __restrict__ srow, int E) {
  int i = blockIdx.x * 256 + threadIdx.x;
  if (i < E) {
    int slot = atomicAdd(&dpad[(long)eidx[E + i] * DPAD + 8], 1);
    srow[slot] = eidx[i];
  }
}

__device__ __forceinline__ f16x8 load_frag8h(const float* p) {
  float4 a = *(const float4*)p;
  float4 b = *(const float4*)(p + 4);
  f16x8 r;
  r[0] = (f16_t)a.x; r[1] = (f16_t)a.y; r[2] = (f16_t)a.z; r[3] = (f16_t)a.w;
  r[4] = (f16_t)b.x; r[5] = (f16_t)b.y; r[6] = (f16_t)b.z; r[7] = (f16_t)b.w;
  return r;
}

// ---------------------------------------------------------------------------
// Shared-memory structs for the role-split kernels (union via char buffer).
// ---------------------------------------------------------------------------
struct GemmSmem {
  f16_t ws_[8][4][64][8];    // 32768 B
  float w1ps[3][128];        //  1536 B
  float bs_[128];            //   512 B
  float pos_s[64][3];        //   768 B
};                           // 35584 B

struct PassASmem {
  unsigned sorted[PA_TILE];       // 8192 B
  unsigned char sbb[PA_TILE];     // 2048 B
  int hist[256];
  int off_[256];
  int cur[256];
  int gbase[256];
  int scanb[256];
};                                // 15360 B

#define SMEM_BYTES 35840

// ---------------------------------------------------------------------------
// AP-GEMM body: 64 nodes/block (r13-proven). A = x@W1x + b1 + pos@W1p,
// P = pos@W1p (f16 into d_out).
// ---------------------------------------------------------------------------
__device__ __forceinline__ void ap_gemm_body(
    const float* __restrict__ x, const float* __restrict__ pos,
    const float* __restrict__ W1, const float* __restrict__ b1,
    f16_t* __restrict__ Abuf, f16_t* __restrict__ Pbuf, int N, int blk,
    char* smem)
{
  GemmSmem* G = (GemmSmem*)smem;
  const int tid = threadIdx.x;
  for (int it = tid; it < 8 * 4 * 64; it += 256) {
    int nt = it >> 8, kt = (it >> 6) & 3, l = it & 63;
    int n = nt * 16 + (l & 15), quad = l >> 4;
    f16x8 v;
#pragma unroll
    for (int j = 0; j < 8; ++j) v[j] = (f16_t)W1[(kt * 32 + quad * 8 + j) * 128 + n];
    *(f16x8*)&G->ws_[nt][kt][l][0] = v;
  }
  for (int it = tid; it < 384; it += 256)
    G->w1ps[it >> 7][it & 127] = W1[(128 + (it >> 7)) * 128 + (it & 127)];
  if (tid < 128) G->bs_[tid] = b1[tid];
  {
    int g = blk * 192 + tid;
    if (tid < 192 && g < 3 * N) G->pos_s[tid / 3][tid % 3] = pos[g];
  }
  __syncthreads();

  const int w = tid >> 6, lane = tid & 63;
  const int m15 = lane & 15, quad = lane >> 4;

  int node_a = blk * 64 + w * 16 + m15;
  const float* xrow = x + (long)min(node_a, N - 1) * 128;
  f16x8 a[4];
#pragma unroll
  for (int kt = 0; kt < 4; ++kt)
    a[kt] = load_frag8h(xrow + kt * 32 + quad * 8);

  f32x4 acc[8];
#pragma unroll
  for (int nt = 0; nt < 8; ++nt) acc[nt] = (f32x4){0.f, 0.f, 0.f, 0.f};
#pragma unroll
  for (int nt = 0; nt < 8; ++nt)
#pragma unroll
    for (int kt = 0; kt < 4; ++kt)
      acc[nt] = __builtin_amdgcn_mfma_f32_16x16x32_f16(
          a[kt], *(const f16x8*)&G->ws_[nt][kt][lane][0], acc[nt], 0, 0, 0);

#pragma unroll
  for (int r = 0; r < 4; ++r) {
    int nl = w * 16 + quad * 4 + r;
    int node = blk * 64 + nl;
    if (node < N) {
      float p0 = G->pos_s[nl][0], p1 = G->pos_s[nl][1], p2 = G->pos_s[nl][2];
#pragma unroll
      for (int nt = 0; nt < 8; ++nt) {
        int c = nt * 16 + m15;
        float pv = p0 * G->w1ps[0][c] + p1 * G->w1ps[1][c] + p2 * G->w1ps[2][c];
        long idx = (long)node * 128 + c;
        Abuf[idx] = (f16_t)(acc[nt][r] + G->bs_[c] + pv);
        Pbuf[idx] = (f16_t)pv;
      }
    }
  }
}

// ---------------------------------------------------------------------------
// passA body (r13-proven): tile-sort PA_TILE edges into superbuckets, all
// random ops in LDS; ~NSB aggregated global atomics per tile; coalesced u32
// segment writes. Entry format: (col&255)<<24 | row.
// ---------------------------------------------------------------------------
__device__ __forceinline__ void passa_body(
    const int* __restrict__ eidx, unsigned* __restrict__ pairsBuf,
    int* __restrict__ superCursor, int E, int tile, char* smem)
{
  PassASmem* S = (PassASmem*)smem;
  const int tid = threadIdx.x;
  const int base = tile * PA_TILE;
  const int cnt_t = min(PA_TILE, E - base);

  for (int j = tid; j < 256; j += 256) S->hist[j] = 0;
  __syncthreads();

  int myrow[8], mycol[8];
#pragma unroll
  for (int k = 0; k < 8; ++k) {
    int idx = k * 256 + tid;
    int i = base + idx;
    if (idx < cnt_t) {
      myrow[k] = eidx[i];
      mycol[k] = eidx[E + i];
      atomicAdd(&S->hist[mycol[k] >> NSB_SHIFT], 1);
    } else mycol[k] = -1;
  }
  __syncthreads();

  int v = S->hist[tid];
  S->scanb[tid] = v;
  __syncthreads();
  for (int d = 1; d < 256; d <<= 1) {
    int t = (tid >= d) ? S->scanb[tid - d] : 0;
    __syncthreads();
    S->scanb[tid] += t;
    __syncthreads();
  }
  int excl = S->scanb[tid] - v;
  S->off_[tid] = excl;
  S->cur[tid]  = excl;
  S->gbase[tid] = (v > 0) ? atomicAdd(&superCursor[tid * 16], v) : 0;
  __syncthreads();

#pragma unroll
  for (int k = 0; k < 8; ++k) {
    if (mycol[k] >= 0) {
      int sb = mycol[k] >> NSB_SHIFT;
      int pos = atomicAdd(&S->cur[sb], 1);
      S->sorted[pos] = ((unsigned)(mycol[k] & 255) << 24) | (unsigned)myrow[k];
      S->sbb[pos] = (unsigned char)sb;
    }
  }
  __syncthreads();

#pragma unroll
  for (int k = 0; k < 8; ++k) {
    int idx = k * 256 + tid;
    if (idx < cnt_t) {
      int sb = S->sbb[idx];
      int local = idx - S->off_[sb];
      int g = S->gbase[sb] + local;
      if (g < SBCAP) pairsBuf[(long)sb * SBCAP + g] = S->sorted[idx];
    }
  }
}

// fusedA: AP-GEMM role + passA role in one launch (overlap).
__global__ __launch_bounds__(256) void fusedA_kernel(
    const float* __restrict__ x, const float* __restrict__ pos,
    const int* __restrict__ eidx, const float* __restrict__ W1,
    const float* __restrict__ b1, unsigned* __restrict__ pairsBuf,
    int* __restrict__ superCursor, f16_t* __restrict__ Abuf,
    f16_t* __restrict__ Pbuf, int N, int E, int nodeBlocks)
{
  __shared__ __align__(16) char smem[SMEM_BYTES];
  if ((int)blockIdx.x >= nodeBlocks) {
    passa_body(eidx, pairsBuf, superCursor, E, (int)blockIdx.x - nodeBlocks, smem);
    return;
  }
  ap_gemm_body(x, pos, W1, b1, Abuf, Pbuf, N, blockIdx.x, smem);
}

// Fallback path: hist role + AP-GEMM role (r7-proven).
__global__ __launch_bounds__(256) void fused_hist_kernel(
    const float* __restrict__ x, const float* __restrict__ pos,
    const int* __restrict__ eidx, const float* __restrict__ W1,
    const float* __restrict__ b1, int* __restrict__ dpad,
    f16_t* __restrict__ Abuf, f16_t* __restrict__ Pbuf,
    int N, int E, int nodeBlocks)
{
  __shared__ __align__(16) char smem[SMEM_BYTES];
  if ((int)blockIdx.x >= nodeBlocks) {
    int i = ((int)blockIdx.x - nodeBlocks) * 256 + threadIdx.x;
    if (i < E) atomicAdd(&dpad[(long)eidx[E + i] * DPAD], 1);
    return;
  }
  ap_gemm_body(x, pos, W1, b1, Abuf, Pbuf, N, blockIdx.x, smem);
}

// ---------------------------------------------------------------------------
// passB: one block per superbucket; exact per-node CSR built in LDS from u32
// pairs. Emits r10-format CSR: srow (row indices), startB[n], endB[n].
// ---------------------------------------------------------------------------
__global__ __launch_bounds__(256) void passb_kernel(
    const unsigned* __restrict__ pairsA, const int* __restrict__ superCursor,
    int* __restrict__ srow, int* __restrict__ startB, int* __restrict__ endB,
    int N)
{
  __shared__ int rows[SBCAP];     // 36 KB
  __shared__ int deg[256], scanb[256], cur[256];
  const int sb = blockIdx.x, tid = threadIdx.x;
  const int cntIn = min(superCursor[sb * 16], SBCAP);
  const unsigned* Pin = pairsA + (long)sb * SBCAP;

  deg[tid] = 0;
  __syncthreads();
  for (int i = tid; i < cntIn; i += 256)
    atomicAdd(&deg[Pin[i] >> 24], 1);
  __syncthreads();
  int d = deg[tid];
  scanb[tid] = d;
  __syncthreads();
  for (int s = 1; s < 256; s <<= 1) {
    int t2 = (tid >= s) ? scanb[tid - s] : 0;
    __syncthreads();
    scanb[tid] += t2;
    __syncthreads();
  }
  int excl = scanb[tid] - d;
  cur[tid] = excl;
  int n = (sb << NSB_SHIFT) + tid;
  if (n < N) {
    startB[n] = sb * SBCAP + excl;
    endB[n]   = sb * SBCAP + excl + d;
  }
  __syncthreads();
  for (int i = tid; i < cntIn; i += 256) {
    unsigned p = Pin[i];
    int slot = atomicAdd(&cur[p >> 24], 1);
    rows[slot] = (int)(p & 0xFFFFFFu);
  }
  __syncthreads();
  const int gb = sb * SBCAP;
  for (int i = tid; i < cntIn; i += 256) srow[gb + i] = rows[i];
}

// ---------------------------------------------------------------------------
// pernode r17: r13-EXACT per-wave body; 512-thread blocks so 8 waves share
// ONE w2s copy (LDS/wave halves -> 32 waves/CU cap, was 16). Residency
// change only — the proven 3-level stream schedule is untouched.
// ---------------------------------------------------------------------------
__global__ __launch_bounds__(512) void pernode_kernel(
    const f16_t* __restrict__ Abuf, const f16_t* __restrict__ Pbuf,
    const float* __restrict__ W2, const float* __restrict__ b2,
    const int* __restrict__ startp, const int* __restrict__ endp,
    const int* __restrict__ srow, f16_t* __restrict__ maxbf, int N)
{
  __shared__ f16_t w2s[8][4][64][8];   // 32 KB, B-fragment-major (shared by 8 waves)
  __shared__ float b2s[128];

  const int tid = threadIdx.x;
  for (int it = tid; it < 8 * 4 * 64; it += 512) {
    int nt = it >> 8, kt = (it >> 6) & 3, l = it & 63;
    int ncol = nt * 16 + (l & 15), q = l >> 4;
    f16x8 v;
#pragma unroll
    for (int j = 0; j < 8; ++j) v[j] = (f16_t)W2[(kt * 32 + q * 8 + j) * 128 + ncol];
    *(f16x8*)&w2s[nt][kt][l][0] = v;
  }
  if (tid < 128) b2s[tid] = b2[tid];
  __syncthreads();

  const int w = tid >> 6, lane = tid & 63;
  const int m15 = lane & 15, quad = lane >> 4;

  const int nslots = (int)gridDim.x * 8;
  const int slot   = (int)blockIdx.x * 8 + w;
  const int K      = (N + nslots - 1) / nslots;
  const int nBeg   = slot * K;
  const int nEnd   = min(N, nBeg + K);
  if (nBeg >= nEnd) return;

  auto adv = [&](int& n, int& c, int& e) {
    c += 16;
    if (c < e) return;
    for (;;) {
      if (++n >= nEnd) { n = nEnd; c -= 16; return; }
      int s_ = startp[n], e_ = endp[n];
      if (e_ > s_) { c = s_; e = e_; return; }
      if (quad == 0) {
#pragma unroll
        for (int nt = 0; nt < 8; ++nt)
          maxbf[(long)n * 128 + nt * 16 + m15] = (f16_t)0.f;
      }
    }
  };

  int n0 = nBeg - 1, c0 = -16, e0 = 0;
  adv(n0, c0, e0);
  if (n0 >= nEnd) return;

  f16x8 PnC[4], PnN[4];
#pragma unroll
  for (int kt = 0; kt < 4; ++kt)
    PnC[kt] = *(const f16x8*)(Pbuf + (long)n0 * 128 + kt * 32 + quad * 8);
  int r0 = srow[min(c0 + m15, e0 - 1)];

  int n1 = n0, c1 = c0, e1 = e0;
  adv(n1, c1, e1);

  f16x8 xv[4];
#pragma unroll
  for (int kt = 0; kt < 4; ++kt)
    xv[kt] = *(const f16x8*)(Abuf + (long)r0 * 128 + kt * 32 + quad * 8);

  int r1 = srow[min(c1 + m15, e1 - 1)];
#pragma unroll
  for (int kt = 0; kt < 4; ++kt) PnN[kt] = PnC[kt];
  if (n1 != n0 && n1 < nEnd) {
#pragma unroll
    for (int kt = 0; kt < 4; ++kt)
      PnN[kt] = *(const f16x8*)(Pbuf + (long)n1 * 128 + kt * 32 + quad * 8);
  }

  int n2 = n1, c2 = c1, e2 = e1;
  adv(n2, c2, e2);
  int r2 = srow[min(c2 + m15, e2 - 1)];

  float runmax[8];
#pragma unroll
  for (int nt = 0; nt < 8; ++nt) runmax[nt] = -3.4e38f;

  for (;;) {
    f16x8 xn[4];
#pragma unroll
    for (int kt = 0; kt < 4; ++kt)
      xn[kt] = *(const f16x8*)(Abuf + (long)r1 * 128 + kt * 32 + quad * 8);

#pragma unroll
    for (int kt = 0; kt < 4; ++kt) xv[kt] = sub_relu8(xv[kt], PnC[kt]);

#pragma unroll
    for (int half = 0; half < 2; ++half) {
      f32x4 a0 = (f32x4){0.f, 0.f, 0.f, 0.f}, a1 = a0, a2 = a0, a3 = a0;
#pragma unroll
      for (int kt = 0; kt < 4; ++kt) {
        a0 = __builtin_amdgcn_mfma_f32_16x16x32_f16(
            xv[kt], *(const f16x8*)&w2s[half * 4 + 0][kt][lane][0], a0, 0, 0, 0);
        a1 = __builtin_amdgcn_mfma_f32_16x16x32_f16(
            xv[kt], *(const f16x8*)&w2s[half * 4 + 1][kt][lane][0], a1, 0, 0, 0);
        a2 = __builtin_amdgcn_mfma_f32_16x16x32_f16(
            xv[kt], *(const f16x8*)&w2s[half * 4 + 2][kt][lane][0], a2, 0, 0, 0);
        a3 = __builtin_amdgcn_mfma_f32_16x16x32_f16(
            xv[kt], *(const f16x8*)&w2s[half * 4 + 3][kt][lane][0], a3, 0, 0, 0);
      }
      runmax[half * 4 + 0] = fmaxf(runmax[half * 4 + 0],
          fmaxf(fmaxf(a0[0], a0[1]), fmaxf(a0[2], a0[3])));
      runmax[half * 4 + 1] = fmaxf(runmax[half * 4 + 1],
          fmaxf(fmaxf(a1[0], a1[1]), fmaxf(a1[2], a1[3])));
      runmax[half * 4 + 2] = fmaxf(runmax[half * 4 + 2],
          fmaxf(fmaxf(a2[0], a2[1]), fmaxf(a2[2], a2[3])));
      runmax[half * 4 + 3] = fmaxf(runmax[half * 4 + 3],
          fmaxf(fmaxf(a3[0], a3[1]), fmaxf(a3[2], a3[3])));
    }

    if (n1 != n0) {
#pragma unroll
      for (int nt = 0; nt < 8; ++nt) {
        float v = runmax[nt];
        v = fmaxf(v, __shfl_xor(v, 16, 64));
        v = fmaxf(v, __shfl_xor(v, 32, 64));
        v += b2s[nt * 16 + m15];
        if (quad == 0) maxbf[(long)n0 * 128 + nt * 16 + m15] = (f16_t)v;
        runmax[nt] = -3.4e38f;
      }
#pragma unroll
      for (int kt = 0; kt < 4; ++kt) PnC[kt] = PnN[kt];
    }

    n0 = n1; c0 = c1; e0 = e1;
    if (n0 >= nEnd) break;
#pragma unroll
    for (int kt = 0; kt < 4; ++kt) xv[kt] = xn[kt];

    n1 = n2; c1 = c2; e1 = e2; r1 = r2;
    if (n1 != n0 && n1 < nEnd) {
#pragma unroll
      for (int kt = 0; kt < 4; ++kt)
        PnN[kt] = *(const f16x8*)(Pbuf + (long)n1 * 128 + kt * 32 + quad * 8);
    }

    adv(n2, c2, e2);
    r2 = srow[min(c2 + m15, e2 - 1)];
  }
}

// ---------------------------------------------------------------------------
// final: d_out = maxbf + x @ Wr + br   (f32 out)
// ---------------------------------------------------------------------------
__global__ __launch_bounds__(256) void final_gemm_kernel(
    const float* __restrict__ xin, const float* __restrict__ W,
    const float* __restrict__ bias, const f16_t* __restrict__ maxv,
    float* __restrict__ dst, int N)
{
  __shared__ f16_t ws_[8][4][64][8];
  __shared__ float bs_[128];

  const int tid = threadIdx.x;
  for (int it = tid; it < 8 * 4 * 64; it += 256) {
    int nt = it >> 8, kt = (it >> 6) & 3, l = it & 63;
    int n = nt * 16 + (l & 15), quad = l >> 4;
    f16x8 v;
#pragma unroll
    for (int j = 0; j < 8; ++j) v[j] = (f16_t)W[(kt * 32 + quad * 8 + j) * 128 + n];
    *(f16x8*)&ws_[nt][kt][l][0] = v;
  }
  if (tid < 128) bs_[tid] = bias[tid];
  __syncthreads();

  const int w = tid >> 6, lane = tid & 63;
  const int m15 = lane & 15, quad = lane >> 4;

  int node_a = blockIdx.x * 64 + w * 16 + m15;
  const float* xrow = xin + (long)min(node_a, N - 1) * 128;
  f16x8 a[4];
#pragma unroll
  for (int kt = 0; kt < 4; ++kt)
    a[kt] = load_frag8h(xrow + kt * 32 + quad * 8);

  f32x4 acc[8];
#pragma unroll
  for (int nt = 0; nt < 8; ++nt) acc[nt] = (f32x4){0.f, 0.f, 0.f, 0.f};
#pragma unroll
  for (int nt = 0; nt < 8; ++nt)
#pragma unroll
    for (int kt = 0; kt < 4; ++kt)
      acc[nt] = __builtin_amdgcn_mfma_f32_16x16x32_f16(
          a[kt], *(const f16x8*)&ws_[nt][kt][lane][0], acc[nt], 0, 0, 0);

#pragma unroll
  for (int r = 0; r < 4; ++r) {
    int node = blockIdx.x * 64 + w * 16 + quad * 4 + r;
    if (node < N) {
#pragma unroll
      for (int nt = 0; nt < 8; ++nt) {
        int c = nt * 16 + m15;
        long idx = (long)node * 128 + c;
        dst[idx] = acc[nt][r] + bs_[c] + (float)maxv[idx];
      }
    }
  }
}

extern "C" void kernel_launch(void* const* d_in, const int* in_sizes, int n_in,
                              void* d_out, int out_size, void* d_ws, size_t ws_size,
                              hipStream_t stream) {
  (void)n_in; (void)out_size;
  const float* x   = (const float*)d_in[0];
  const float* pos = (const float*)d_in[1];
  const int*   eix = (const int*)d_in[2];
  const float* W1  = (const float*)d_in[3];
  const float* b1  = (const float*)d_in[4];
  const float* W2  = (const float*)d_in[5];
  const float* b2  = (const float*)d_in[6];
  const float* Wr  = (const float*)d_in[7];
  const float* br  = (const float*)d_in[8];

  const int N = in_sizes[0] / 128;
  const int E = in_sizes[2] / 2;

  f16_t* Abuf = (f16_t*)d_out;                      // [0, N*128) f16
  f16_t* Pbuf = (f16_t*)d_out + (size_t)N * 128;    // [N*128, N*256) f16

  const int nodeBlocks = (N + 63) / 64;
  const int edgeBlocks = (E + 255) / 256;
  const int nTiles     = (N + 255) / 256;
  const int NSB        = (N + 255) >> NSB_SHIFT;
  const int paBlocks   = (E + PA_TILE - 1) / PA_TILE;

  f16_t* maxbf = (f16_t*)d_ws;                      // N*256 B

  // packed path ws: maxbf + pairsA + srow + start/end + superCursor
  const size_t needPack = (size_t)N * 256 + (size_t)NSB * SBCAP * 8 +
                          (size_t)N * 8 + (size_t)NSB * 64 + 1024;

  if (ws_size >= needPack && NSB <= 256 && N < (1 << 24)) {
    // ---------------- u32-bucketed CSR path ----------------
    unsigned* pairsA      = (unsigned*)((char*)d_ws + (size_t)N * 256);
    int*      srowN       = (int*)(pairsA + (size_t)NSB * SBCAP);
    int*      startB      = (int*)(srowN + (size_t)NSB * SBCAP);
    int*      endB        = startB + N;
    int*      superCursor = endB + N;

    hipMemsetAsync(superCursor, 0, (size_t)NSB * 64, stream);
    fusedA_kernel<<<nodeBlocks + paBlocks, 256, 0, stream>>>(
        x, pos, eix, W1, b1, pairsA, superCursor, Abuf, Pbuf, N, E, nodeBlocks);
    passb_kernel<<<NSB, 256, 0, stream>>>(pairsA, superCursor, srowN,
                                          startB, endB, N);
    pernode_kernel<<<1024, 512, 0, stream>>>(Abuf, Pbuf, W2, b2, startB, endB,
                                             srowN, maxbf, N);
  } else {
    // ---------------- fallback: r7 hist+scan+scatter ----------------
    int* srow  = (int*)((char*)d_ws + (size_t)N * 256);
    int* dpad  = srow + E;
    int* start = dpad + (size_t)N * DPAD;
    int* tsum  = start + N + 1;
    int* texcl = tsum + 256;

    hipMemsetAsync(dpad, 0, (size_t)N * DPAD * 4, stream);
    fused_hist_kernel<<<nodeBlocks + edgeBlocks, 256, 0, stream>>>(
        x, pos, eix, W1, b1, dpad, Abuf, Pbuf, N, E, nodeBlocks);
    tilesum_kernel<<<nTiles, 256, 0, stream>>>(dpad, tsum, N);
    tscan_kernel<<<1, 256, 0, stream>>>(tsum, texcl, &start[N], nTiles);
    scanout_kernel<<<nTiles, 256, 0, stream>>>(dpad, texcl, start, N);
    scatter_kernel<<<edgeBlocks, 256, 0, stream>>>(eix, dpad, srow, E);
    pernode_kernel<<<1024, 512, 0, stream>>>(Abuf, Pbuf, W2, b2, start, start + 1,
                                             srow, maxbf, N);
  }

  final_gemm_kernel<<<nodeBlocks, 256, 0, stream>>>(x, Wr, br, maxbf,
                                                    (float*)d_out, N);
}

// Round 11
// 269.870 us; speedup vs baseline: 1.2285x; 1.0240x over previous
//
#include <hip/hip_runtime.h>
#include <hip/hip_bf16.h>

// PointNetConv on MI355X (gfx950) — round 18. f32 inputs.
// Algebra: h1 = relu(A[row] - P[col]),  A = x@W1x + b1 + pos@W1p,  P = pos@W1p.
//
// r17 post-mortem: 512-thread w2s-sharing was null (134us, occ unchanged) —
// VGPR=124 caps 16 waves/CU regardless of LDS. pernode is bound by the
// ~20G random-line-op/s fabric ceiling (2.4M fetch-lines @ 18.6G/s = 121us
// floor; measured 130). Remaining levers (fp8 A, row-bucketing) are
// precision-risky / net-negative on paper. Five schedule perturbations all
// regressed: r13's pernode is the converged point.
//
// r18: PURE REVERT to the measured-best r13 configuration (267.4us):
// pernode 256-thread/2048-block r13-exact; r13 fusedA/passA/passB/final.

typedef _Float16 f16_t;
typedef _Float16 f16x8 __attribute__((ext_vector_type(8)));
typedef float    f32x4 __attribute__((ext_vector_type(4)));

#define DPAD 16
#define NSB_SHIFT 8          // 256 nodes per superbucket
#define SBCAP 9216           // per-bucket edge cap (mean 8192, +11 sigma)
#define PA_TILE 2048         // edges per passA tile

__device__ __forceinline__ f16x8 sub_relu8(f16x8 a, f16x8 b) {
  f16x8 d = a - b;                          // v_pk_add_f16 (neg)
  f16x8 z = {};
  return __builtin_elementwise_max(d, z);   // v_pk_max_f16
}

// ---------------- fallback scan chain (proven r7) ----------------
__global__ __launch_bounds__(256) void tilesum_kernel(const int* __restrict__ dpad,
                                                      int* __restrict__ tsum, int N) {
  __shared__ int ws[4];
  int tid = threadIdx.x;
  int i = blockIdx.x * 256 + tid;
  int v = (i < N) ? dpad[(long)i * DPAD] : 0;
#pragma unroll
  for (int off = 32; off > 0; off >>= 1) v += __shfl_down(v, off, 64);
  if ((tid & 63) == 0) ws[tid >> 6] = v;
  __syncthreads();
  if (tid == 0) tsum[blockIdx.x] = ws[0] + ws[1] + ws[2] + ws[3];
}

__global__ __launch_bounds__(256) void tscan_kernel(const int* __restrict__ tsum,
                                                    int* __restrict__ texcl,
                                                    int* __restrict__ startN, int nt_) {
  __shared__ int wsum[4];
  int tid = threadIdx.x, lane = tid & 63, w = tid >> 6;
  int v = (tid < nt_) ? tsum[tid] : 0;
  int s = v;
#pragma unroll
  for (int off = 1; off < 64; off <<= 1) {
    int t = __shfl_up(s, off, 64);
    if (lane >= off) s += t;
  }
  if (lane == 63) wsum[w] = s;
  __syncthreads();
  int add = 0;
  for (int j = 0; j < w; ++j) add += wsum[j];
  if (tid < nt_) texcl[tid] = add + s - v;
  if (tid == 0) *startN = wsum[0] + wsum[1] + wsum[2] + wsum[3];
}

__global__ __launch_bounds__(256) void scanout_kernel(int* __restrict__ dpad,
                                                      const int* __restrict__ texcl,
                                                      int* __restrict__ start, int N) {
  __shared__ int wsum[4];
  int tid = threadIdx.x, lane = tid & 63, w = tid >> 6;
  int i = blockIdx.x * 256 + tid;
  int v = (i < N) ? dpad[(long)i * DPAD] : 0;
  int s = v;
#pragma unroll
  for (int off = 1; off < 64; off <<= 1) {
    int t = __shfl_up(s, off, 64);
    if (lane >= off) s += t;
  }
  if (lane == 63) wsum[w] = s;
  __syncthreads();
  int add = texcl[blockIdx.x];
  for (int j = 0; j < w; ++j) add += wsum[j];
  int excl = add + s - v;
  if (i < N) { start[i] = excl; dpad[(long)i * DPAD + 8] = excl; }
}

__global__ __launch_bounds__(256) void scatter_kernel(const int* __restrict__ eidx,
                                                      int* __restrict__ dpad,
                                                      int* __restrict__ srow, int E) {
  int i = blockIdx.x * 256 + threadIdx.x;
  if (i < E) {
    int slot = atomicAdd(&dpad[(long)eidx[E + i] * DPAD + 8], 1);
    srow[slot] = eidx[i];
  }
}

__device__ __forceinline__ f16x8 load_frag8h(const float* p) {
  float4 a = *(const float4*)p;
  float4 b = *(const float4*)(p + 4);
  f16x8 r;
  r[0] = (f16_t)a.x; r[1] = (f16_t)a.y; r[2] = (f16_t)a.z; r[3] = (f16_t)a.w;
  r[4] = (f16_t)b.x; r[5] = (f16_t)b.y; r[6] = (f16_t)b.z; r[7] = (f16_t)b.w;
  return r;
}

// ---------------------------------------------------------------------------
// Shared-memory structs for the role-split kernels (union via char buffer).
// ---------------------------------------------------------------------------
struct GemmSmem {
  f16_t ws_[8][4][64][8];    // 32768 B
  float w1ps[3][128];        //  1536 B
  float bs_[128];            //   512 B
  float pos_s[64][3];        //   768 B
};                           // 35584 B

struct PassASmem {
  unsigned sorted[PA_TILE];       // 8192 B
  unsigned char sbb[PA_TILE];     // 2048 B
  int hist[256];
  int off_[256];
  int cur[256];
  int gbase[256];
  int scanb[256];
};                                // 15360 B

#define SMEM_BYTES 35840

// ---------------------------------------------------------------------------
// AP-GEMM body: A = x@W1x + b1 + pos@W1p, P = pos@W1p (f16 into d_out).
// ---------------------------------------------------------------------------
__device__ __forceinline__ void ap_gemm_body(
    const float* __restrict__ x, const float* __restrict__ pos,
    const float* __restrict__ W1, const float* __restrict__ b1,
    f16_t* __restrict__ Abuf, f16_t* __restrict__ Pbuf, int N, int blk,
    char* smem)
{
  GemmSmem* G = (GemmSmem*)smem;
  const int tid = threadIdx.x;
  for (int it = tid; it < 8 * 4 * 64; it += 256) {
    int nt = it >> 8, kt = (it >> 6) & 3, l = it & 63;
    int n = nt * 16 + (l & 15), quad = l >> 4;
    f16x8 v;
#pragma unroll
    for (int j = 0; j < 8; ++j) v[j] = (f16_t)W1[(kt * 32 + quad * 8 + j) * 128 + n];
    *(f16x8*)&G->ws_[nt][kt][l][0] = v;
  }
  for (int it = tid; it < 384; it += 256)
    G->w1ps[it >> 7][it & 127] = W1[(128 + (it >> 7)) * 128 + (it & 127)];
  if (tid < 128) G->bs_[tid] = b1[tid];
  {
    int g = blk * 192 + tid;
    if (tid < 192 && g < 3 * N) G->pos_s[tid / 3][tid % 3] = pos[g];
  }
  __syncthreads();

  const int w = tid >> 6, lane = tid & 63;
  const int m15 = lane & 15, quad = lane >> 4;

  int node_a = blk * 64 + w * 16 + m15;
  const float* xrow = x + (long)min(node_a, N - 1) * 128;
  f16x8 a[4];
#pragma unroll
  for (int kt = 0; kt < 4; ++kt)
    a[kt] = load_frag8h(xrow + kt * 32 + quad * 8);

  f32x4 acc[8];
#pragma unroll
  for (int nt = 0; nt < 8; ++nt) acc[nt] = (f32x4){0.f, 0.f, 0.f, 0.f};
#pragma unroll
  for (int nt = 0; nt < 8; ++nt)
#pragma unroll
    for (int kt = 0; kt < 4; ++kt)
      acc[nt] = __builtin_amdgcn_mfma_f32_16x16x32_f16(
          a[kt], *(const f16x8*)&G->ws_[nt][kt][lane][0], acc[nt], 0, 0, 0);

#pragma unroll
  for (int r = 0; r < 4; ++r) {
    int nl = w * 16 + quad * 4 + r;
    int node = blk * 64 + nl;
    if (node < N) {
      float p0 = G->pos_s[nl][0], p1 = G->pos_s[nl][1], p2 = G->pos_s[nl][2];
#pragma unroll
      for (int nt = 0; nt < 8; ++nt) {
        int c = nt * 16 + m15;
        float pv = p0 * G->w1ps[0][c] + p1 * G->w1ps[1][c] + p2 * G->w1ps[2][c];
        long idx = (long)node * 128 + c;
        Abuf[idx] = (f16_t)(acc[nt][r] + G->bs_[c] + pv);
        Pbuf[idx] = (f16_t)pv;
      }
    }
  }
}

// ---------------------------------------------------------------------------
// passA body: tile-sort PA_TILE edges into superbuckets, all random ops in
// LDS; ~NSB aggregated global atomics per tile; coalesced u32 segment writes.
// Entry format: (col&255)<<24 | row.
// ---------------------------------------------------------------------------
__device__ __forceinline__ void passa_body(
    const int* __restrict__ eidx, unsigned* __restrict__ pairsBuf,
    int* __restrict__ superCursor, int E, int tile, char* smem)
{
  PassASmem* S = (PassASmem*)smem;
  const int tid = threadIdx.x;
  const int base = tile * PA_TILE;
  const int cnt_t = min(PA_TILE, E - base);

  for (int j = tid; j < 256; j += 256) S->hist[j] = 0;
  __syncthreads();

  int myrow[8], mycol[8];
#pragma unroll
  for (int k = 0; k < 8; ++k) {
    int idx = k * 256 + tid;
    int i = base + idx;
    if (idx < cnt_t) {
      myrow[k] = eidx[i];
      mycol[k] = eidx[E + i];
      atomicAdd(&S->hist[mycol[k] >> NSB_SHIFT], 1);
    } else mycol[k] = -1;
  }
  __syncthreads();

  int v = S->hist[tid];
  S->scanb[tid] = v;
  __syncthreads();
  for (int d = 1; d < 256; d <<= 1) {
    int t = (tid >= d) ? S->scanb[tid - d] : 0;
    __syncthreads();
    S->scanb[tid] += t;
    __syncthreads();
  }
  int excl = S->scanb[tid] - v;
  S->off_[tid] = excl;
  S->cur[tid]  = excl;
  S->gbase[tid] = (v > 0) ? atomicAdd(&superCursor[tid * 16], v) : 0;
  __syncthreads();

#pragma unroll
  for (int k = 0; k < 8; ++k) {
    if (mycol[k] >= 0) {
      int sb = mycol[k] >> NSB_SHIFT;
      int pos = atomicAdd(&S->cur[sb], 1);
      S->sorted[pos] = ((unsigned)(mycol[k] & 255) << 24) | (unsigned)myrow[k];
      S->sbb[pos] = (unsigned char)sb;
    }
  }
  __syncthreads();

#pragma unroll
  for (int k = 0; k < 8; ++k) {
    int idx = k * 256 + tid;
    if (idx < cnt_t) {
      int sb = S->sbb[idx];
      int local = idx - S->off_[sb];
      int g = S->gbase[sb] + local;
      if (g < SBCAP) pairsBuf[(long)sb * SBCAP + g] = S->sorted[idx];
    }
  }
}

// fusedA: AP-GEMM role + passA role in one launch (overlap).
__global__ __launch_bounds__(256) void fusedA_kernel(
    const float* __restrict__ x, const float* __restrict__ pos,
    const int* __restrict__ eidx, const float* __restrict__ W1,
    const float* __restrict__ b1, unsigned* __restrict__ pairsBuf,
    int* __restrict__ superCursor, f16_t* __restrict__ Abuf,
    f16_t* __restrict__ Pbuf, int N, int E, int nodeBlocks)
{
  __shared__ __align__(16) char smem[SMEM_BYTES];
  if ((int)blockIdx.x >= nodeBlocks) {
    passa_body(eidx, pairsBuf, superCursor, E, (int)blockIdx.x - nodeBlocks, smem);
    return;
  }
  ap_gemm_body(x, pos, W1, b1, Abuf, Pbuf, N, blockIdx.x, smem);
}

// Fallback path: hist role + AP-GEMM role (r7-proven).
__global__ __launch_bounds__(256) void fused_hist_kernel(
    const float* __restrict__ x, const float* __restrict__ pos,
    const int* __restrict__ eidx, const float* __restrict__ W1,
    const float* __restrict__ b1, int* __restrict__ dpad,
    f16_t* __restrict__ Abuf, f16_t* __restrict__ Pbuf,
    int N, int E, int nodeBlocks)
{
  __shared__ __align__(16) char smem[SMEM_BYTES];
  if ((int)blockIdx.x >= nodeBlocks) {
    int i = ((int)blockIdx.x - nodeBlocks) * 256 + threadIdx.x;
    if (i < E) atomicAdd(&dpad[(long)eidx[E + i] * DPAD], 1);
    return;
  }
  ap_gemm_body(x, pos, W1, b1, Abuf, Pbuf, N, blockIdx.x, smem);
}

// ---------------------------------------------------------------------------
// passB: one block per superbucket; exact per-node CSR built in LDS from u32
// pairs. Emits r10-format CSR: srow (row indices), startB[n], endB[n].
// ---------------------------------------------------------------------------
__global__ __launch_bounds__(256) void passb_kernel(
    const unsigned* __restrict__ pairsA, const int* __restrict__ superCursor,
    int* __restrict__ srow, int* __restrict__ startB, int* __restrict__ endB,
    int N)
{
  __shared__ int rows[SBCAP];     // 36 KB
  __shared__ int deg[256], scanb[256], cur[256];
  const int sb = blockIdx.x, tid = threadIdx.x;
  const int cntIn = min(superCursor[sb * 16], SBCAP);
  const unsigned* Pin = pairsA + (long)sb * SBCAP;

  deg[tid] = 0;
  __syncthreads();
  for (int i = tid; i < cntIn; i += 256)
    atomicAdd(&deg[Pin[i] >> 24], 1);
  __syncthreads();
  int d = deg[tid];
  scanb[tid] = d;
  __syncthreads();
  for (int s = 1; s < 256; s <<= 1) {
    int t2 = (tid >= s) ? scanb[tid - s] : 0;
    __syncthreads();
    scanb[tid] += t2;
    __syncthreads();
  }
  int excl = scanb[tid] - d;
  cur[tid] = excl;
  int n = (sb << NSB_SHIFT) + tid;
  if (n < N) {
    startB[n] = sb * SBCAP + excl;
    endB[n]   = sb * SBCAP + excl + d;
  }
  __syncthreads();
  for (int i = tid; i < cntIn; i += 256) {
    unsigned p = Pin[i];
    int slot = atomicAdd(&cur[p >> 24], 1);
    rows[slot] = (int)(p & 0xFFFFFFu);
  }
  __syncthreads();
  const int gb = sb * SBCAP;
  for (int i = tid; i < cntIn; i += 256) srow[gb + i] = rows[i];
}

// ---------------------------------------------------------------------------
// pernode (r13-EXACT, proven 129.8-131us): continuous (node,chunk) stream per
// wave; 3-level pipeline crossing node boundaries (srow 2 ahead, A-gather +
// next-node P 1 ahead, compute level-0). Do not perturb (r14/r15/r17 lost).
// ---------------------------------------------------------------------------
__global__ __launch_bounds__(256) void pernode_kernel(
    const f16_t* __restrict__ Abuf, const f16_t* __restrict__ Pbuf,
    const float* __restrict__ W2, const float* __restrict__ b2,
    const int* __restrict__ startp, const int* __restrict__ endp,
    const int* __restrict__ srow, f16_t* __restrict__ maxbf, int N)
{
  __shared__ f16_t w2s[8][4][64][8];   // 32 KB, B-fragment-major
  __shared__ float b2s[128];

  const int tid = threadIdx.x;
  for (int it = tid; it < 8 * 4 * 64; it += 256) {
    int nt = it >> 8, kt = (it >> 6) & 3, l = it & 63;
    int ncol = nt * 16 + (l & 15), q = l >> 4;
    f16x8 v;
#pragma unroll
    for (int j = 0; j < 8; ++j) v[j] = (f16_t)W2[(kt * 32 + q * 8 + j) * 128 + ncol];
    *(f16x8*)&w2s[nt][kt][l][0] = v;
  }
  if (tid < 128) b2s[tid] = b2[tid];
  __syncthreads();

  const int w = tid >> 6, lane = tid & 63;
  const int m15 = lane & 15, quad = lane >> 4;

  const int nslots = (int)gridDim.x * 4;
  const int slot   = (int)blockIdx.x * 4 + w;
  const int K      = (N + nslots - 1) / nslots;
  const int nBeg   = slot * K;
  const int nEnd   = min(N, nBeg + K);
  if (nBeg >= nEnd) return;

  auto adv = [&](int& n, int& c, int& e) {
    c += 16;
    if (c < e) return;
    for (;;) {
      if (++n >= nEnd) { n = nEnd; c -= 16; return; }
      int s_ = startp[n], e_ = endp[n];
      if (e_ > s_) { c = s_; e = e_; return; }
      if (quad == 0) {
#pragma unroll
        for (int nt = 0; nt < 8; ++nt)
          maxbf[(long)n * 128 + nt * 16 + m15] = (f16_t)0.f;
      }
    }
  };

  int n0 = nBeg - 1, c0 = -16, e0 = 0;
  adv(n0, c0, e0);
  if (n0 >= nEnd) return;

  f16x8 PnC[4], PnN[4];
#pragma unroll
  for (int kt = 0; kt < 4; ++kt)
    PnC[kt] = *(const f16x8*)(Pbuf + (long)n0 * 128 + kt * 32 + quad * 8);
  int r0 = srow[min(c0 + m15, e0 - 1)];

  int n1 = n0, c1 = c0, e1 = e0;
  adv(n1, c1, e1);

  f16x8 xv[4];
#pragma unroll
  for (int kt = 0; kt < 4; ++kt)
    xv[kt] = *(const f16x8*)(Abuf + (long)r0 * 128 + kt * 32 + quad * 8);

  int r1 = srow[min(c1 + m15, e1 - 1)];
#pragma unroll
  for (int kt = 0; kt < 4; ++kt) PnN[kt] = PnC[kt];
  if (n1 != n0 && n1 < nEnd) {
#pragma unroll
    for (int kt = 0; kt < 4; ++kt)
      PnN[kt] = *(const f16x8*)(Pbuf + (long)n1 * 128 + kt * 32 + quad * 8);
  }

  int n2 = n1, c2 = c1, e2 = e1;
  adv(n2, c2, e2);
  int r2 = srow[min(c2 + m15, e2 - 1)];

  float runmax[8];
#pragma unroll
  for (int nt = 0; nt < 8; ++nt) runmax[nt] = -3.4e38f;

  for (;;) {
    f16x8 xn[4];
#pragma unroll
    for (int kt = 0; kt < 4; ++kt)
      xn[kt] = *(const f16x8*)(Abuf + (long)r1 * 128 + kt * 32 + quad * 8);

#pragma unroll
    for (int kt = 0; kt < 4; ++kt) xv[kt] = sub_relu8(xv[kt], PnC[kt]);

#pragma unroll
    for (int half = 0; half < 2; ++half) {
      f32x4 a0 = (f32x4){0.f, 0.f, 0.f, 0.f}, a1 = a0, a2 = a0, a3 = a0;
#pragma unroll
      for (int kt = 0; kt < 4; ++kt) {
        a0 = __builtin_amdgcn_mfma_f32_16x16x32_f16(
            xv[kt], *(const f16x8*)&w2s[half * 4 + 0][kt][lane][0], a0, 0, 0, 0);
        a1 = __builtin_amdgcn_mfma_f32_16x16x32_f16(
            xv[kt], *(const f16x8*)&w2s[half * 4 + 1][kt][lane][0], a1, 0, 0, 0);
        a2 = __builtin_amdgcn_mfma_f32_16x16x32_f16(
            xv[kt], *(const f16x8*)&w2s[half * 4 + 2][kt][lane][0], a2, 0, 0, 0);
        a3 = __builtin_amdgcn_mfma_f32_16x16x32_f16(
            xv[kt], *(const f16x8*)&w2s[half * 4 + 3][kt][lane][0], a3, 0, 0, 0);
      }
      runmax[half * 4 + 0] = fmaxf(runmax[half * 4 + 0],
          fmaxf(fmaxf(a0[0], a0[1]), fmaxf(a0[2], a0[3])));
      runmax[half * 4 + 1] = fmaxf(runmax[half * 4 + 1],
          fmaxf(fmaxf(a1[0], a1[1]), fmaxf(a1[2], a1[3])));
      runmax[half * 4 + 2] = fmaxf(runmax[half * 4 + 2],
          fmaxf(fmaxf(a2[0], a2[1]), fmaxf(a2[2], a2[3])));
      runmax[half * 4 + 3] = fmaxf(runmax[half * 4 + 3],
          fmaxf(fmaxf(a3[0], a3[1]), fmaxf(a3[2], a3[3])));
    }

    if (n1 != n0) {
#pragma unroll
      for (int nt = 0; nt < 8; ++nt) {
        float v = runmax[nt];
        v = fmaxf(v, __shfl_xor(v, 16, 64));
        v = fmaxf(v, __shfl_xor(v, 32, 64));
        v += b2s[nt * 16 + m15];
        if (quad == 0) maxbf[(long)n0 * 128 + nt * 16 + m15] = (f16_t)v;
        runmax[nt] = -3.4e38f;
      }
#pragma unroll
      for (int kt = 0; kt < 4; ++kt) PnC[kt] = PnN[kt];
    }

    n0 = n1; c0 = c1; e0 = e1;
    if (n0 >= nEnd) break;
#pragma unroll
    for (int kt = 0; kt < 4; ++kt) xv[kt] = xn[kt];

    n1 = n2; c1 = c2; e1 = e2; r1 = r2;
    if (n1 != n0 && n1 < nEnd) {
#pragma unroll
      for (int kt = 0; kt < 4; ++kt)
        PnN[kt] = *(const f16x8*)(Pbuf + (long)n1 * 128 + kt * 32 + quad * 8);
    }

    adv(n2, c2, e2);
    r2 = srow[min(c2 + m15, e2 - 1)];
  }
}

// ---------------------------------------------------------------------------
// final: d_out = maxbf + x @ Wr + br   (f32 out)
// ---------------------------------------------------------------------------
__global__ __launch_bounds__(256) void final_gemm_kernel(
    const float* __restrict__ xin, const float* __restrict__ W,
    const float* __restrict__ bias, const f16_t* __restrict__ maxv,
    float* __restrict__ dst, int N)
{
  __shared__ f16_t ws_[8][4][64][8];
  __shared__ float bs_[128];

  const int tid = threadIdx.x;
  for (int it = tid; it < 8 * 4 * 64; it += 256) {
    int nt = it >> 8, kt = (it >> 6) & 3, l = it & 63;
    int n = nt * 16 + (l & 15), quad = l >> 4;
    f16x8 v;
#pragma unroll
    for (int j = 0; j < 8; ++j) v[j] = (f16_t)W[(kt * 32 + quad * 8 + j) * 128 + n];
    *(f16x8*)&ws_[nt][kt][l][0] = v;
  }
  if (tid < 128) bs_[tid] = bias[tid];
  __syncthreads();

  const int w = tid >> 6, lane = tid & 63;
  const int m15 = lane & 15, quad = lane >> 4;

  int node_a = blockIdx.x * 64 + w * 16 + m15;
  const float* xrow = xin + (long)min(node_a, N - 1) * 128;
  f16x8 a[4];
#pragma unroll
  for (int kt = 0; kt < 4; ++kt)
    a[kt] = load_frag8h(xrow + kt * 32 + quad * 8);

  f32x4 acc[8];
#pragma unroll
  for (int nt = 0; nt < 8; ++nt) acc[nt] = (f32x4){0.f, 0.f, 0.f, 0.f};
#pragma unroll
  for (int nt = 0; nt < 8; ++nt)
#pragma unroll
    for (int kt = 0; kt < 4; ++kt)
      acc[nt] = __builtin_amdgcn_mfma_f32_16x16x32_f16(
          a[kt], *(const f16x8*)&ws_[nt][kt][lane][0], acc[nt], 0, 0, 0);

#pragma unroll
  for (int r = 0; r < 4; ++r) {
    int node = blockIdx.x * 64 + w * 16 + quad * 4 + r;
    if (node < N) {
#pragma unroll
      for (int nt = 0; nt < 8; ++nt) {
        int c = nt * 16 + m15;
        long idx = (long)node * 128 + c;
        dst[idx] = acc[nt][r] + bs_[c] + (float)maxv[idx];
      }
    }
  }
}

extern "C" void kernel_launch(void* const* d_in, const int* in_sizes, int n_in,
                              void* d_out, int out_size, void* d_ws, size_t ws_size,
                              hipStream_t stream) {
  (void)n_in; (void)out_size;
  const float* x   = (const float*)d_in[0];
  const float* pos = (const float*)d_in[1];
  const int*   eix = (const int*)d_in[2];
  const float* W1  = (const float*)d_in[3];
  const float* b1  = (const float*)d_in[4];
  const float* W2  = (const float*)d_in[5];
  const float* b2  = (const float*)d_in[6];
  const float* Wr  = (const float*)d_in[7];
  const float* br  = (const float*)d_in[8];

  const int N = in_sizes[0] / 128;
  const int E = in_sizes[2] / 2;

  f16_t* Abuf = (f16_t*)d_out;                      // [0, N*128) f16
  f16_t* Pbuf = (f16_t*)d_out + (size_t)N * 128;    // [N*128, N*256) f16

  const int nodeBlocks = (N + 63) / 64;
  const int edgeBlocks = (E + 255) / 256;
  const int nTiles     = (N + 255) / 256;
  const int NSB        = (N + 255) >> NSB_SHIFT;
  const int paBlocks   = (E + PA_TILE - 1) / PA_TILE;

  f16_t* maxbf = (f16_t*)d_ws;                      // N*256 B

  // packed path ws: maxbf + pairsA + srow + start/end + superCursor
  const size_t needPack = (size_t)N * 256 + (size_t)NSB * SBCAP * 8 +
                          (size_t)N * 8 + (size_t)NSB * 64 + 1024;

  if (ws_size >= needPack && NSB <= 256 && N < (1 << 24)) {
    // ---------------- u32-bucketed CSR path ----------------
    unsigned* pairsA      = (unsigned*)((char*)d_ws + (size_t)N * 256);
    int*      srowN       = (int*)(pairsA + (size_t)NSB * SBCAP);
    int*      startB      = (int*)(srowN + (size_t)NSB * SBCAP);
    int*      endB        = startB + N;
    int*      superCursor = endB + N;

    hipMemsetAsync(superCursor, 0, (size_t)NSB * 64, stream);
    fusedA_kernel<<<nodeBlocks + paBlocks, 256, 0, stream>>>(
        x, pos, eix, W1, b1, pairsA, superCursor, Abuf, Pbuf, N, E, nodeBlocks);
    passb_kernel<<<NSB, 256, 0, stream>>>(pairsA, superCursor, srowN,
                                          startB, endB, N);
    pernode_kernel<<<2048, 256, 0, stream>>>(Abuf, Pbuf, W2, b2, startB, endB,
                                             srowN, maxbf, N);
  } else {
    // ---------------- fallback: r7 hist+scan+scatter ----------------
    int* srow  = (int*)((char*)d_ws + (size_t)N * 256);
    int* dpad  = srow + E;
    int* start = dpad + (size_t)N * DPAD;
    int* tsum  = start + N + 1;
    int* texcl = tsum + 256;

    hipMemsetAsync(dpad, 0, (size_t)N * DPAD * 4, stream);
    fused_hist_kernel<<<nodeBlocks + edgeBlocks, 256, 0, stream>>>(
        x, pos, eix, W1, b1, dpad, Abuf, Pbuf, N, E, nodeBlocks);
    tilesum_kernel<<<nTiles, 256, 0, stream>>>(dpad, tsum, N);
    tscan_kernel<<<1, 256, 0, stream>>>(tsum, texcl, &start[N], nTiles);
    scanout_kernel<<<nTiles, 256, 0, stream>>>(dpad, texcl, start, N);
    scatter_kernel<<<edgeBlocks, 256, 0, stream>>>(eix, dpad, srow, E);
    pernode_kernel<<<2048, 256, 0, stream>>>(Abuf, Pbuf, W2, b2, start, start + 1,
                                             srow, maxbf, N);
  }

  final_gemm_kernel<<<nodeBlocks, 256, 0, stream>>>(x, Wr, br, maxbf,
                                                    (float*)d_out, N);
}